// Round 2
// baseline (1417.692 us; speedup 1.0000x reference)
//
#include <hip/hip_runtime.h>
#include <hip/hip_bf16.h>
#include <math.h>

// Problem constants
#define Bc   2
#define Lc   2048
#define DMc  1536
#define Hc   12
#define FDc  16
#define DVc  128
#define D2c  256
#define CHK  128
#define NCH  16
#define ROWS (Bc*Lc)          // 4096
#define HFD  (Hc*FDc)         // 192
#define HDV  (Hc*DVc)         // 1536

__device__ __forceinline__ float bf2f(unsigned short u) {
    return __uint_as_float(((unsigned int)u) << 16);
}
__device__ __forceinline__ unsigned short f2bf(float v) {
    unsigned int u = __float_as_uint(v);
    unsigned int r = (u + 0x7FFFu + ((u >> 16) & 1u)) >> 16;
    return (unsigned short)r;
}
// flagged input load: isf32 ? f32 : bf16
__device__ __forceinline__ float ldin(const void* p, size_t i, int isf32) {
    return isf32 ? ((const float*)p)[i] : bf2f(((const unsigned short*)p)[i]);
}
__device__ __forceinline__ float scrubf(float v) {
    return (fabsf(v) < 1e30f) ? v : 0.f;   // NaN compares false -> 0
}

// ---------------------------------------------------------------------------
// Dtype probe: bf16 data -> even-indexed bf16 elems have sane exponents (~100%).
// f32 data read as bf16 -> even elems are f32 low-mantissa bits: random exponent
// (~24% sane). Writes flag: 0 = bf16, 1 = f32.
// ---------------------------------------------------------------------------
__global__ void probe_dtype(const unsigned short* __restrict__ hs, int* __restrict__ flag) {
    const int tid = threadIdx.x;
    int sane = 0;
    for (int i = tid; i < 1024; i += 256) {
        unsigned short b = hs[2 * i];
        int e = (b >> 7) & 0xFF;
        if (e >= 97 && e <= 157) sane++;
    }
    __shared__ int tot;
    if (tid == 0) tot = 0;
    __syncthreads();
    atomicAdd(&tot, sane);
    __syncthreads();
    if (tid == 0) *flag = (tot >= 614) ? 0 : 1;
}

// ---------------------------------------------------------------------------
// Tiled GEMM: C(MxN) = A(MxK) @ B(KxN), row-major. 64x64 tile, 256 thr, 4x4 micro.
// aMode/bMode/cMode: 0 = always f32, 1 = dtype per flag (f32 if flag else bf16).
// ---------------------------------------------------------------------------
__global__ __launch_bounds__(256) void gemm_tiled(const void* __restrict__ A,
                                                  const void* __restrict__ B,
                                                  void* __restrict__ C,
                                                  int M, int N, int K,
                                                  int aMode, int bMode, int cMode, int scrub,
                                                  const int* __restrict__ flagp) {
    const int f = *flagp;
    const int aF = aMode ? f : 1;
    const int bF = bMode ? f : 1;
    const int cF = cMode ? f : 1;
    __shared__ __align__(16) float As[16][68];
    __shared__ __align__(16) float Bs[16][68];
    const int tx = threadIdx.x, ty = threadIdx.y;
    const int tid = ty * 16 + tx;
    const int row0 = blockIdx.y * 64;
    const int col0 = blockIdx.x * 64;
    const int mty = ty * 4, ntx = tx * 4;
    float acc[4][4] = {};
    for (int k0 = 0; k0 < K; k0 += 16) {
#pragma unroll
        for (int u = 0; u < 4; u++) {
            int idx = tid + u * 256;
            int m = idx >> 4, kk = idx & 15;
            As[kk][m] = ldin(A, (size_t)(row0 + m) * K + k0 + kk, aF);
        }
#pragma unroll
        for (int u = 0; u < 4; u++) {
            int idx = tid + u * 256;
            int kk = idx >> 6, nn = idx & 63;
            Bs[kk][nn] = ldin(B, (size_t)(k0 + kk) * N + col0 + nn, bF);
        }
        __syncthreads();
#pragma unroll
        for (int kk = 0; kk < 16; kk++) {
            float4 a4 = *(const float4*)&As[kk][mty];
            float4 b4 = *(const float4*)&Bs[kk][ntx];
            float av[4] = {a4.x, a4.y, a4.z, a4.w};
            float bv[4] = {b4.x, b4.y, b4.z, b4.w};
#pragma unroll
            for (int i = 0; i < 4; i++)
#pragma unroll
                for (int j = 0; j < 4; j++) acc[i][j] += av[i] * bv[j];
        }
        __syncthreads();
    }
#pragma unroll
    for (int i = 0; i < 4; i++)
#pragma unroll
        for (int j = 0; j < 4; j++) {
            float vv = acc[i][j];
            if (scrub) vv = scrubf(vv);
            size_t idx = (size_t)(row0 + mty + i) * N + col0 + ntx + j;
            if (cF) ((float*)C)[idx] = vv;
            else    ((unsigned short*)C)[idx] = f2bf(vv);
        }
}

// ---------------------------------------------------------------------------
// Fused LayerNorm (last dim = 192) for q and k, in place on f32 buffers.
// ---------------------------------------------------------------------------
__global__ __launch_bounds__(192) void ln_kernel(float* __restrict__ q, float* __restrict__ k,
                                                 const void* __restrict__ gq,
                                                 const void* __restrict__ bq,
                                                 const void* __restrict__ gk,
                                                 const void* __restrict__ bk,
                                                 const int* __restrict__ flagp) {
    const int f = *flagp;
    const int row = blockIdx.x, t = threadIdx.x;
    float vq = q[(size_t)row * HFD + t];
    float vk = k[(size_t)row * HFD + t];
    float s[4] = {vq, vq * vq, vk, vk * vk};
    __shared__ float part[4][3];
    const int w = t >> 6, lane = t & 63;
#pragma unroll
    for (int i = 0; i < 4; i++) {
        float v = s[i];
        for (int off = 32; off; off >>= 1) v += __shfl_down(v, off);
        if (lane == 0) part[i][w] = v;
    }
    __syncthreads();
    float sq  = part[0][0] + part[0][1] + part[0][2];
    float sq2 = part[1][0] + part[1][1] + part[1][2];
    float sk  = part[2][0] + part[2][1] + part[2][2];
    float sk2 = part[3][0] + part[3][1] + part[3][2];
    const float inv = 1.0f / (float)HFD;
    float muq = sq * inv, muk = sk * inv;
    float varq = sq2 * inv - muq * muq;
    float vark = sk2 * inv - muk * muk;
    float oq = (vq - muq) * rsqrtf(varq + 1e-5f) * ldin(gq, t, f) + ldin(bq, t, f);
    float ok = (vk - muk) * rsqrtf(vark + 1e-5f) * ldin(gk, t, f) + ldin(bk, t, f);
    q[(size_t)row * HFD + t] = oq;
    k[(size_t)row * HFD + t] = ok;
}

// ---------------------------------------------------------------------------
// Per-chunk local state: Sc[d2][dv] = sum_c k2[c][d2]*v[c][dv], zc[d2]=sum_c k2[c][d2]
// ---------------------------------------------------------------------------
__global__ __launch_bounds__(256) void chunk_state_kernel(const float* __restrict__ kn,
                                                          const float* __restrict__ v,
                                                          float* __restrict__ Sc,
                                                          float* __restrict__ zc) {
    const int blk = blockIdx.x;
    const int n = blk & 15, bh = blk >> 4;
    const int h = bh % Hc, b = bh / Hc;
    const int row0 = b * Lc + n * CHK;
    const int tid = threadIdx.x;
    __shared__ float kcs[CHK * FDc];
    for (int u = tid; u < CHK * FDc; u += 256) {
        int c = u >> 4, ff = u & 15;
        kcs[u] = kn[(size_t)(row0 + c) * HFD + h * FDc + ff];
    }
    __syncthreads();
    const int i = tid >> 4, j = tid & 15;
    float4 acc[32];
#pragma unroll
    for (int d = 0; d < 32; d++) acc[d] = make_float4(0.f, 0.f, 0.f, 0.f);
    float zacc = 0.f;
    for (int c = 0; c < CHK; c++) {
        float sk = kcs[c * 16 + i] * kcs[c * 16 + j] * 0.25f;
        zacc += sk;
        const float4* vr = (const float4*)(v + (size_t)(row0 + c) * HDV + h * DVc);
#pragma unroll
        for (int d = 0; d < 32; d++) {
            float4 vv = vr[d];
            acc[d].x += sk * vv.x; acc[d].y += sk * vv.y;
            acc[d].z += sk * vv.z; acc[d].w += sk * vv.w;
        }
    }
    float4* outp = (float4*)(Sc + (size_t)blk * (D2c * DVc) + (size_t)tid * DVc);
#pragma unroll
    for (int d = 0; d < 32; d++) outp[d] = acc[d];
    zc[blk * D2c + tid] = zacc;
}

// ---------------------------------------------------------------------------
// Exclusive prefix over the 16 chunks (in place).
// ---------------------------------------------------------------------------
__global__ __launch_bounds__(256) void sprefix_kernel(float* __restrict__ S) {
    const int bh = blockIdx.y;
    const int elem = blockIdx.x * 256 + threadIdx.x;
    size_t base = (size_t)bh * NCH * (D2c * DVc) + elem;
    float a = 0.f;
#pragma unroll
    for (int n = 0; n < NCH; n++) {
        float t = S[base + (size_t)n * (D2c * DVc)];
        S[base + (size_t)n * (D2c * DVc)] = a;
        a += t;
    }
}

__global__ __launch_bounds__(256) void zprefix_kernel(float* __restrict__ z) {
    const int bh = blockIdx.x;
    size_t base = (size_t)bh * NCH * D2c + threadIdx.x;
    float a = 0.f;
#pragma unroll
    for (int n = 0; n < NCH; n++) {
        float t = z[base + (size_t)n * D2c];
        z[base + (size_t)n * D2c] = a;
        a += t;
    }
}

// ---------------------------------------------------------------------------
// Per-chunk output. o = (q2 @ Sstate + (A*tril) @ v) / (q2@z + rowsum(A) + eps)
// A[c][e] = (dot16(q[c],k[e]))^2 / 16 (Taylor dot identity).
// ---------------------------------------------------------------------------
__global__ __launch_bounds__(256) void chunk_out_kernel(const float* __restrict__ qn,
                                                        const float* __restrict__ kn,
                                                        const float* __restrict__ v,
                                                        const float* __restrict__ S,
                                                        const float* __restrict__ z,
                                                        float* __restrict__ o) {
    const int blk = blockIdx.x;
    const int n = blk & 15, bh = blk >> 4;
    const int h = bh % Hc, b = bh / Hc;
    const int row0 = b * Lc + n * CHK;
    const int tid = threadIdx.x;

    __shared__ __align__(16) float qcs[CHK * FDc];           // 8 KB, persistent
    __shared__ __align__(16) unsigned char regionB[41984];   // phase1: Stile(16K)+zl(1K); phase2: kcs(8K)+At(32K)
    __shared__ float denl[CHK];
    __shared__ float rs2[2][CHK];

    float* Stile = (float*)regionB;                          // [32*128]
    float* zl = (float*)(regionB + 16384);                   // [256]
    float* kcs = (float*)regionB;                            // [128*16]
    unsigned short* At = (unsigned short*)(regionB + 8192);  // [128*128] bf16 bits, e-major

    for (int u = tid; u < CHK * FDc; u += 256) {
        int c = u >> 4, ff = u & 15;
        qcs[u] = qn[(size_t)(row0 + c) * HFD + h * FDc + ff];
    }
    zl[tid] = z[(size_t)bh * (NCH * D2c) + n * D2c + tid];
    __syncthreads();

    const int ci = tid >> 4, dvi = tid & 15;
    const int c0 = ci * 8, dv0 = dvi * 8;
    float acc[8][8] = {};
    float den1[8] = {};
    const size_t Sbase = (size_t)blk * (D2c * DVc);

    // Phase 1: num1 = q2 @ Sstate, den1 = q2 @ zstate
    for (int ti = 0; ti < 8; ti++) {
        for (int u = tid; u < 1024; u += 256)
            ((float4*)Stile)[u] = ((const float4*)(S + Sbase + (size_t)ti * 4096))[u];
        __syncthreads();
        for (int d2l = 0; d2l < 32; d2l++) {
            int d2 = ti * 32 + d2l;
            int i = d2 >> 4, j = d2 & 15;
            float zv = zl[d2];
            float4 s0 = *(const float4*)&Stile[d2l * 128 + dv0];
            float4 s1 = *(const float4*)&Stile[d2l * 128 + dv0 + 4];
#pragma unroll
            for (int cc = 0; cc < 8; cc++) {
                float q2v = qcs[(c0 + cc) * 16 + i] * qcs[(c0 + cc) * 16 + j] * 0.25f;
                den1[cc] += q2v * zv;
                acc[cc][0] += q2v * s0.x; acc[cc][1] += q2v * s0.y;
                acc[cc][2] += q2v * s0.z; acc[cc][3] += q2v * s0.w;
                acc[cc][4] += q2v * s1.x; acc[cc][5] += q2v * s1.y;
                acc[cc][6] += q2v * s1.z; acc[cc][7] += q2v * s1.w;
            }
        }
        __syncthreads();
    }
    if (dvi == 0) {
#pragma unroll
        for (int cc = 0; cc < 8; cc++) denl[c0 + cc] = den1[cc];
    }
    for (int u = tid; u < CHK * FDc; u += 256) {
        int c = u >> 4, ff = u & 15;
        kcs[u] = kn[(size_t)(row0 + c) * HFD + h * FDc + ff];
    }
    __syncthreads();

    // Phase 2a: masked A (bf16 bits) + row sums
    {
        const int c = tid & 127, eb = tid >> 7;
        float qr[16];
#pragma unroll
        for (int ff = 0; ff < 16; ff++) qr[ff] = qcs[c * 16 + ff];
        float rs = 0.f;
        for (int ee = 0; ee < 64; ee++) {
            int e = eb * 64 + ee;
            float dot = 0.f;
#pragma unroll
            for (int ff = 0; ff < 16; ff++) dot += qr[ff] * kcs[e * 16 + ff];
            float a = (e <= c) ? dot * dot * 0.0625f : 0.f;
            rs += a;
            At[e * 128 + c] = f2bf(a);
        }
        rs2[eb][c] = rs;
    }
    __syncthreads();

    // Phase 2b: num2 = A @ v
    const float* vb = v + (size_t)row0 * HDV + h * DVc + dv0;
    for (int e = 0; e < CHK; e++) {
        const unsigned short* ap = At + e * 128 + c0;
        float4 v0 = *(const float4*)(vb + (size_t)e * HDV);
        float4 v1 = *(const float4*)(vb + (size_t)e * HDV + 4);
        float af[8];
#pragma unroll
        for (int cc = 0; cc < 8; cc++) af[cc] = bf2f(ap[cc]);
#pragma unroll
        for (int cc = 0; cc < 8; cc++) {
            acc[cc][0] += af[cc] * v0.x; acc[cc][1] += af[cc] * v0.y;
            acc[cc][2] += af[cc] * v0.z; acc[cc][3] += af[cc] * v0.w;
            acc[cc][4] += af[cc] * v1.x; acc[cc][5] += af[cc] * v1.y;
            acc[cc][6] += af[cc] * v1.z; acc[cc][7] += af[cc] * v1.w;
        }
    }

    // Epilogue with non-finite scrub
#pragma unroll
    for (int cc = 0; cc < 8; cc++) {
        float den = denl[c0 + cc] + rs2[0][c0 + cc] + rs2[1][c0 + cc] + 1e-12f;
        float r = 1.0f / den;
        float ov[8];
#pragma unroll
        for (int j = 0; j < 8; j++) ov[j] = scrubf(acc[cc][j] * r);
        float* op = o + (size_t)(row0 + c0 + cc) * HDV + h * DVc + dv0;
        *(float4*)op       = make_float4(ov[0], ov[1], ov[2], ov[3]);
        *(float4*)(op + 4) = make_float4(ov[4], ov[5], ov[6], ov[7]);
    }
}

// ---------------------------------------------------------------------------
extern "C" void kernel_launch(void* const* d_in, const int* in_sizes, int n_in,
                              void* d_out, int out_size, void* d_ws, size_t ws_size,
                              hipStream_t stream) {
    const void* hs = d_in[0];
    const void* Wq = d_in[1];
    const void* Wk = d_in[2];
    const void* Wv = d_in[3];
    const void* Wo = d_in[4];
    const void* gq = d_in[5];
    const void* bq = d_in[6];
    const void* gk = d_in[7];
    const void* bk = d_in[8];

    int* flag = (int*)d_ws;
    float* base = (float*)d_ws + 16;
    float* qpre = base;                      // 4096*192
    float* kpre = qpre + (size_t)ROWS * HFD;
    float* v    = kpre + (size_t)ROWS * HFD; // 4096*1536
    float* Sc   = v + (size_t)ROWS * HDV;    // 384*256*128
    float* zc   = Sc + (size_t)Bc * Hc * NCH * D2c * DVc;
    float* o    = zc + (size_t)Bc * Hc * NCH * D2c;

    probe_dtype<<<1, 256, 0, stream>>>((const unsigned short*)hs, flag);

    dim3 blk2d(16, 16);
    gemm_tiled<<<dim3(HFD / 64, ROWS / 64), blk2d, 0, stream>>>(
        hs, Wq, qpre, ROWS, HFD, DMc, 1, 1, 0, 0, flag);
    gemm_tiled<<<dim3(HFD / 64, ROWS / 64), blk2d, 0, stream>>>(
        hs, Wk, kpre, ROWS, HFD, DMc, 1, 1, 0, 0, flag);
    gemm_tiled<<<dim3(HDV / 64, ROWS / 64), blk2d, 0, stream>>>(
        hs, Wv, v, ROWS, HDV, DMc, 1, 1, 0, 0, flag);
    ln_kernel<<<ROWS, HFD, 0, stream>>>(qpre, kpre, gq, bq, gk, bk, flag);
    chunk_state_kernel<<<Bc * Hc * NCH, 256, 0, stream>>>(kpre, v, Sc, zc);
    sprefix_kernel<<<dim3((D2c * DVc) / 256, Bc * Hc), 256, 0, stream>>>(Sc);
    zprefix_kernel<<<Bc * Hc, 256, 0, stream>>>(zc);
    chunk_out_kernel<<<Bc * Hc * NCH, 256, 0, stream>>>(qpre, kpre, v, Sc, zc, o);
    // Final projection: A = o (always f32 ws), B = Wo (flagged), C = out (flagged), scrub on
    gemm_tiled<<<dim3(HDV / 64, ROWS / 64), blk2d, 0, stream>>>(
        o, Wo, d_out, ROWS, HDV, DMc, 0, 1, 1, 1, flag);
}

// Round 3
// 962.140 us; speedup vs baseline: 1.4735x; 1.4735x over previous
//
#include <hip/hip_runtime.h>
#include <hip/hip_bf16.h>
#include <math.h>

// Problem constants
#define Bc   2
#define Lc   2048
#define DMc  1536
#define Hc   12
#define FDc  16
#define DVc  128
#define D2c  256
#define CHK  128
#define NCH  16
#define ROWS (Bc*Lc)          // 4096
#define HFD  (Hc*FDc)         // 192
#define HDV  (Hc*DVc)         // 1536

typedef unsigned short ushortx;
typedef __bf16 bf16x8 __attribute__((ext_vector_type(8)));
typedef float f32x4 __attribute__((ext_vector_type(4)));

__device__ __forceinline__ float bf2f(unsigned short u) {
    return __uint_as_float(((unsigned int)u) << 16);
}
__device__ __forceinline__ unsigned short f2bf(float v) {
    unsigned int u = __float_as_uint(v);
    unsigned int r = (u + 0x7FFFu + ((u >> 16) & 1u)) >> 16;
    return (unsigned short)r;
}
__device__ __forceinline__ float ldin(const void* p, size_t i, int isf32) {
    return isf32 ? ((const float*)p)[i] : bf2f(((const unsigned short*)p)[i]);
}
__device__ __forceinline__ float scrubf(float v) {
    return (fabsf(v) < 1e30f) ? v : 0.f;
}

#define GLL16(g, l) __builtin_amdgcn_global_load_lds( \
    (const __attribute__((address_space(1))) unsigned int*)(g), \
    (__attribute__((address_space(3))) unsigned int*)(l), 16, 0, 0)

// ---------------------------------------------------------------------------
// Dtype probe: writes flag 0 = bf16 data, 1 = f32 data.
// ---------------------------------------------------------------------------
__global__ void probe_dtype(const unsigned short* __restrict__ hs, int* __restrict__ flag) {
    const int tid = threadIdx.x;
    int sane = 0;
    for (int i = tid; i < 1024; i += 256) {
        unsigned short b = hs[2 * i];
        int e = (b >> 7) & 0xFF;
        if (e >= 97 && e <= 157) sane++;
    }
    __shared__ int tot;
    if (tid == 0) tot = 0;
    __syncthreads();
    atomicAdd(&tot, sane);
    __syncthreads();
    if (tid == 0) *flag = (tot >= 614) ? 0 : 1;
}

// ---------------------------------------------------------------------------
// Elementwise convert to bf16 (4 elems/thread). n divisible by 1024.
// ---------------------------------------------------------------------------
__global__ __launch_bounds__(256) void conv_bf16(const void* __restrict__ X,
                                                 unsigned short* __restrict__ Y,
                                                 int n4, const int* __restrict__ flagp) {
    const int f = *flagp;
    int i = blockIdx.x * 256 + threadIdx.x;
    if (i >= n4) return;
    if (f) {
        float4 x = ((const float4*)X)[i];
        ushort4 y;
        y.x = f2bf(x.x); y.y = f2bf(x.y); y.z = f2bf(x.z); y.w = f2bf(x.w);
        ((ushort4*)Y)[i] = y;
    } else {
        ((ushort4*)Y)[i] = ((const ushort4*)X)[i];
    }
}

// ---------------------------------------------------------------------------
// Transpose + convert: Wt[n][k] = bf16(W[k][n]). rows=K, cols=N, 64x64 tiles.
// ---------------------------------------------------------------------------
__global__ __launch_bounds__(256) void convT_bf16(const void* __restrict__ W,
                                                  unsigned short* __restrict__ Wt,
                                                  int rows, int cols,
                                                  const int* __restrict__ flagp) {
    const int f = *flagp;
    __shared__ float tile[64][65];
    const int t = threadIdx.x;
    const int bx = blockIdx.x * 64;  // n
    const int by = blockIdx.y * 64;  // k
#pragma unroll
    for (int u = 0; u < 16; u++) {
        int idx = t + u * 256;
        int r = idx >> 6, c = idx & 63;
        tile[r][c] = ldin(W, (size_t)(by + r) * cols + bx + c, f);
    }
    __syncthreads();
#pragma unroll
    for (int u = 0; u < 16; u++) {
        int idx = t + u * 256;
        int r = idx >> 6, c = idx & 63;   // r = n-local, c = k-local
        Wt[(size_t)(bx + r) * rows + by + c] = f2bf(tile[c][r]);
    }
}

// ---------------------------------------------------------------------------
// MFMA bf16 GEMM: C(MxN) = A(MxK) @ Bt(NxK)^T. 128x128 tile, 4 waves,
// each wave a 64x64 subtile of 4x4 16x16x32 MFMAs. global_load_lds staging.
// cMode: 0 = C f32, 1 = C bf16, 2 = flagged (f32 if flag else bf16).
// M,N % 128 == 0, K % 32 == 0.
// ---------------------------------------------------------------------------
__global__ __launch_bounds__(256) void gemm_mfma_bt(const unsigned short* __restrict__ A,
                                                    const unsigned short* __restrict__ Bt,
                                                    void* __restrict__ C,
                                                    int M, int N, int K,
                                                    int cMode, const int* __restrict__ flagp) {
    const int f = *flagp;
    const bool cF32 = (cMode == 0) || (cMode == 2 && f == 1);
    __shared__ __align__(16) unsigned short As[128 * 32];
    __shared__ __align__(16) unsigned short Bs[128 * 32];
    const int tid = threadIdx.x;
    const int wave = tid >> 6, lane = tid & 63;
    const int row0 = blockIdx.y * 128, col0 = blockIdx.x * 128;
    const int wrow = (wave >> 1) * 64, wcol = (wave & 1) * 64;
    const int mlane = lane & 15, quad = lane >> 4;

    const unsigned short* Ab = A + (size_t)row0 * K;
    const unsigned short* Bb = Bt + (size_t)col0 * K;
    const int r0 = tid >> 2;
    const int kc = (tid & 3) * 8;
    const size_t off0 = (size_t)r0 * K + kc;
    const size_t off1 = (size_t)(r0 + 64) * K + kc;
    char* AsW = (char*)As + wave * 1024;
    char* BsW = (char*)Bs + wave * 1024;

    f32x4 acc[4][4] = {};

    for (int k0 = 0; k0 < K; k0 += 32) {
        GLL16(Ab + off0 + k0, AsW);
        GLL16(Ab + off1 + k0, AsW + 4096);
        GLL16(Bb + off0 + k0, BsW);
        GLL16(Bb + off1 + k0, BsW + 4096);
        __syncthreads();
        bf16x8 a[4], b[4];
#pragma unroll
        for (int i = 0; i < 4; i++)
            a[i] = *(const bf16x8*)&As[(wrow + i * 16 + mlane) * 32 + quad * 8];
#pragma unroll
        for (int j = 0; j < 4; j++)
            b[j] = *(const bf16x8*)&Bs[(wcol + j * 16 + mlane) * 32 + quad * 8];
#pragma unroll
        for (int i = 0; i < 4; i++)
#pragma unroll
            for (int j = 0; j < 4; j++)
                acc[i][j] = __builtin_amdgcn_mfma_f32_16x16x32_bf16(a[i], b[j], acc[i][j], 0, 0, 0);
        __syncthreads();
    }

#pragma unroll
    for (int i = 0; i < 4; i++)
#pragma unroll
        for (int j = 0; j < 4; j++) {
            const int col = col0 + wcol + j * 16 + mlane;
#pragma unroll
            for (int r = 0; r < 4; r++) {
                const int row = row0 + wrow + i * 16 + quad * 4 + r;
                float vv = acc[i][j][r];
                if (cF32) ((float*)C)[(size_t)row * N + col] = vv;
                else      ((unsigned short*)C)[(size_t)row * N + col] = f2bf(vv);
            }
        }
}

// ---------------------------------------------------------------------------
// VALU tiled GEMM (kept for the two small N=192 projections).
// ---------------------------------------------------------------------------
__global__ __launch_bounds__(256) void gemm_tiled(const void* __restrict__ A,
                                                  const void* __restrict__ B,
                                                  void* __restrict__ C,
                                                  int M, int N, int K,
                                                  int aMode, int bMode, int cMode, int scrub,
                                                  const int* __restrict__ flagp) {
    const int f = *flagp;
    const int aF = aMode ? f : 1;
    const int bF = bMode ? f : 1;
    const int cF = cMode ? f : 1;
    __shared__ __align__(16) float As[16][68];
    __shared__ __align__(16) float Bs[16][68];
    const int tx = threadIdx.x, ty = threadIdx.y;
    const int tid = ty * 16 + tx;
    const int row0 = blockIdx.y * 64;
    const int col0 = blockIdx.x * 64;
    const int mty = ty * 4, ntx = tx * 4;
    float acc[4][4] = {};
    for (int k0 = 0; k0 < K; k0 += 16) {
#pragma unroll
        for (int u = 0; u < 4; u++) {
            int idx = tid + u * 256;
            int m = idx >> 4, kk = idx & 15;
            As[kk][m] = ldin(A, (size_t)(row0 + m) * K + k0 + kk, aF);
        }
#pragma unroll
        for (int u = 0; u < 4; u++) {
            int idx = tid + u * 256;
            int kk = idx >> 6, nn = idx & 63;
            Bs[kk][nn] = ldin(B, (size_t)(k0 + kk) * N + col0 + nn, bF);
        }
        __syncthreads();
#pragma unroll
        for (int kk = 0; kk < 16; kk++) {
            float4 a4 = *(const float4*)&As[kk][mty];
            float4 b4 = *(const float4*)&Bs[kk][ntx];
            float av[4] = {a4.x, a4.y, a4.z, a4.w};
            float bv[4] = {b4.x, b4.y, b4.z, b4.w};
#pragma unroll
            for (int i = 0; i < 4; i++)
#pragma unroll
                for (int j = 0; j < 4; j++) acc[i][j] += av[i] * bv[j];
        }
        __syncthreads();
    }
#pragma unroll
    for (int i = 0; i < 4; i++)
#pragma unroll
        for (int j = 0; j < 4; j++) {
            float vv = acc[i][j];
            if (scrub) vv = scrubf(vv);
            size_t idx = (size_t)(row0 + mty + i) * N + col0 + ntx + j;
            if (cF) ((float*)C)[idx] = vv;
            else    ((unsigned short*)C)[idx] = f2bf(vv);
        }
}

// ---------------------------------------------------------------------------
// Fused LayerNorm (last dim = 192) for q and k, in place on f32 buffers.
// ---------------------------------------------------------------------------
__global__ __launch_bounds__(192) void ln_kernel(float* __restrict__ q, float* __restrict__ k,
                                                 const void* __restrict__ gq,
                                                 const void* __restrict__ bq,
                                                 const void* __restrict__ gk,
                                                 const void* __restrict__ bk,
                                                 const int* __restrict__ flagp) {
    const int f = *flagp;
    const int row = blockIdx.x, t = threadIdx.x;
    float vq = q[(size_t)row * HFD + t];
    float vk = k[(size_t)row * HFD + t];
    float s[4] = {vq, vq * vq, vk, vk * vk};
    __shared__ float part[4][3];
    const int w = t >> 6, lane = t & 63;
#pragma unroll
    for (int i = 0; i < 4; i++) {
        float v = s[i];
        for (int off = 32; off; off >>= 1) v += __shfl_down(v, off);
        if (lane == 0) part[i][w] = v;
    }
    __syncthreads();
    float sq  = part[0][0] + part[0][1] + part[0][2];
    float sq2 = part[1][0] + part[1][1] + part[1][2];
    float sk  = part[2][0] + part[2][1] + part[2][2];
    float sk2 = part[3][0] + part[3][1] + part[3][2];
    const float inv = 1.0f / (float)HFD;
    float muq = sq * inv, muk = sk * inv;
    float varq = sq2 * inv - muq * muq;
    float vark = sk2 * inv - muk * muk;
    float oq = (vq - muq) * rsqrtf(varq + 1e-5f) * ldin(gq, t, f) + ldin(bq, t, f);
    float ok = (vk - muk) * rsqrtf(vark + 1e-5f) * ldin(gk, t, f) + ldin(bk, t, f);
    q[(size_t)row * HFD + t] = oq;
    k[(size_t)row * HFD + t] = ok;
}

// ---------------------------------------------------------------------------
// Per-chunk local state: Sc[d2][dv] = sum_c k2[c][d2]*v[c][dv], zc[d2]=sum_c k2[c][d2]
// ---------------------------------------------------------------------------
__global__ __launch_bounds__(256) void chunk_state_kernel(const float* __restrict__ kn,
                                                          const float* __restrict__ v,
                                                          float* __restrict__ Sc,
                                                          float* __restrict__ zc) {
    const int blk = blockIdx.x;
    const int n = blk & 15, bh = blk >> 4;
    const int h = bh % Hc, b = bh / Hc;
    const int row0 = b * Lc + n * CHK;
    const int tid = threadIdx.x;
    __shared__ float kcs[CHK * FDc];
    for (int u = tid; u < CHK * FDc; u += 256) {
        int c = u >> 4, ff = u & 15;
        kcs[u] = kn[(size_t)(row0 + c) * HFD + h * FDc + ff];
    }
    __syncthreads();
    const int i = tid >> 4, j = tid & 15;
    float4 acc[32];
#pragma unroll
    for (int d = 0; d < 32; d++) acc[d] = make_float4(0.f, 0.f, 0.f, 0.f);
    float zacc = 0.f;
    for (int c = 0; c < CHK; c++) {
        float sk = kcs[c * 16 + i] * kcs[c * 16 + j] * 0.25f;
        zacc += sk;
        const float4* vr = (const float4*)(v + (size_t)(row0 + c) * HDV + h * DVc);
#pragma unroll
        for (int d = 0; d < 32; d++) {
            float4 vv = vr[d];
            acc[d].x += sk * vv.x; acc[d].y += sk * vv.y;
            acc[d].z += sk * vv.z; acc[d].w += sk * vv.w;
        }
    }
    float4* outp = (float4*)(Sc + (size_t)blk * (D2c * DVc) + (size_t)tid * DVc);
#pragma unroll
    for (int d = 0; d < 32; d++) outp[d] = acc[d];
    zc[blk * D2c + tid] = zacc;
}

// ---------------------------------------------------------------------------
// Exclusive prefix over the 16 chunks (in place).
// ---------------------------------------------------------------------------
__global__ __launch_bounds__(256) void sprefix_kernel(float* __restrict__ S) {
    const int bh = blockIdx.y;
    const int elem = blockIdx.x * 256 + threadIdx.x;
    size_t base = (size_t)bh * NCH * (D2c * DVc) + elem;
    float a = 0.f;
#pragma unroll
    for (int n = 0; n < NCH; n++) {
        float t = S[base + (size_t)n * (D2c * DVc)];
        S[base + (size_t)n * (D2c * DVc)] = a;
        a += t;
    }
}

__global__ __launch_bounds__(256) void zprefix_kernel(float* __restrict__ z) {
    const int bh = blockIdx.x;
    size_t base = (size_t)bh * NCH * D2c + threadIdx.x;
    float a = 0.f;
#pragma unroll
    for (int n = 0; n < NCH; n++) {
        float t = z[base + (size_t)n * D2c];
        z[base + (size_t)n * D2c] = a;
        a += t;
    }
}

// ---------------------------------------------------------------------------
// Per-chunk output. o = (q2 @ Sstate + (A*tril) @ v) / (q2@z + rowsum(A) + eps)
// Output written as bf16 (feeds the MFMA out-projection).
// ---------------------------------------------------------------------------
__global__ __launch_bounds__(256) void chunk_out_kernel(const float* __restrict__ qn,
                                                        const float* __restrict__ kn,
                                                        const float* __restrict__ v,
                                                        const float* __restrict__ S,
                                                        const float* __restrict__ z,
                                                        unsigned short* __restrict__ o) {
    const int blk = blockIdx.x;
    const int n = blk & 15, bh = blk >> 4;
    const int h = bh % Hc, b = bh / Hc;
    const int row0 = b * Lc + n * CHK;
    const int tid = threadIdx.x;

    __shared__ __align__(16) float qcs[CHK * FDc];
    __shared__ __align__(16) unsigned char regionB[41984];
    __shared__ float denl[CHK];
    __shared__ float rs2[2][CHK];

    float* Stile = (float*)regionB;                          // [32*128]
    float* zl = (float*)(regionB + 16384);                   // [256]
    float* kcs = (float*)regionB;                            // [128*16]
    unsigned short* At = (unsigned short*)(regionB + 8192);  // [128*128] bf16 bits, e-major

    for (int u = tid; u < CHK * FDc; u += 256) {
        int c = u >> 4, ff = u & 15;
        qcs[u] = qn[(size_t)(row0 + c) * HFD + h * FDc + ff];
    }
    zl[tid] = z[(size_t)bh * (NCH * D2c) + n * D2c + tid];
    __syncthreads();

    const int ci = tid >> 4, dvi = tid & 15;
    const int c0 = ci * 8, dv0 = dvi * 8;
    float acc[8][8] = {};
    float den1[8] = {};
    const size_t Sbase = (size_t)blk * (D2c * DVc);

    for (int ti = 0; ti < 8; ti++) {
        for (int u = tid; u < 1024; u += 256)
            ((float4*)Stile)[u] = ((const float4*)(S + Sbase + (size_t)ti * 4096))[u];
        __syncthreads();
        for (int d2l = 0; d2l < 32; d2l++) {
            int d2 = ti * 32 + d2l;
            int i = d2 >> 4, j = d2 & 15;
            float zv = zl[d2];
            float4 s0 = *(const float4*)&Stile[d2l * 128 + dv0];
            float4 s1 = *(const float4*)&Stile[d2l * 128 + dv0 + 4];
#pragma unroll
            for (int cc = 0; cc < 8; cc++) {
                float q2v = qcs[(c0 + cc) * 16 + i] * qcs[(c0 + cc) * 16 + j] * 0.25f;
                den1[cc] += q2v * zv;
                acc[cc][0] += q2v * s0.x; acc[cc][1] += q2v * s0.y;
                acc[cc][2] += q2v * s0.z; acc[cc][3] += q2v * s0.w;
                acc[cc][4] += q2v * s1.x; acc[cc][5] += q2v * s1.y;
                acc[cc][6] += q2v * s1.z; acc[cc][7] += q2v * s1.w;
            }
        }
        __syncthreads();
    }
    if (dvi == 0) {
#pragma unroll
        for (int cc = 0; cc < 8; cc++) denl[c0 + cc] = den1[cc];
    }
    for (int u = tid; u < CHK * FDc; u += 256) {
        int c = u >> 4, ff = u & 15;
        kcs[u] = kn[(size_t)(row0 + c) * HFD + h * FDc + ff];
    }
    __syncthreads();

    {
        const int c = tid & 127, eb = tid >> 7;
        float qr[16];
#pragma unroll
        for (int ff = 0; ff < 16; ff++) qr[ff] = qcs[c * 16 + ff];
        float rs = 0.f;
        for (int ee = 0; ee < 64; ee++) {
            int e = eb * 64 + ee;
            float dot = 0.f;
#pragma unroll
            for (int ff = 0; ff < 16; ff++) dot += qr[ff] * kcs[e * 16 + ff];
            float a = (e <= c) ? dot * dot * 0.0625f : 0.f;
            rs += a;
            At[e * 128 + c] = f2bf(a);
        }
        rs2[eb][c] = rs;
    }
    __syncthreads();

    const float* vb = v + (size_t)row0 * HDV + h * DVc + dv0;
    for (int e = 0; e < CHK; e++) {
        const unsigned short* ap = At + e * 128 + c0;
        float4 v0 = *(const float4*)(vb + (size_t)e * HDV);
        float4 v1 = *(const float4*)(vb + (size_t)e * HDV + 4);
        float af[8];
#pragma unroll
        for (int cc = 0; cc < 8; cc++) af[cc] = bf2f(ap[cc]);
#pragma unroll
        for (int cc = 0; cc < 8; cc++) {
            acc[cc][0] += af[cc] * v0.x; acc[cc][1] += af[cc] * v0.y;
            acc[cc][2] += af[cc] * v0.z; acc[cc][3] += af[cc] * v0.w;
            acc[cc][4] += af[cc] * v1.x; acc[cc][5] += af[cc] * v1.y;
            acc[cc][6] += af[cc] * v1.z; acc[cc][7] += af[cc] * v1.w;
        }
    }

#pragma unroll
    for (int cc = 0; cc < 8; cc++) {
        float den = denl[c0 + cc] + rs2[0][c0 + cc] + rs2[1][c0 + cc] + 1e-12f;
        float r = 1.0f / den;
        ushort4 y0, y1;
        y0.x = f2bf(scrubf(acc[cc][0] * r)); y0.y = f2bf(scrubf(acc[cc][1] * r));
        y0.z = f2bf(scrubf(acc[cc][2] * r)); y0.w = f2bf(scrubf(acc[cc][3] * r));
        y1.x = f2bf(scrubf(acc[cc][4] * r)); y1.y = f2bf(scrubf(acc[cc][5] * r));
        y1.z = f2bf(scrubf(acc[cc][6] * r)); y1.w = f2bf(scrubf(acc[cc][7] * r));
        unsigned short* op = o + (size_t)(row0 + c0 + cc) * HDV + h * DVc + dv0;
        *(ushort4*)op       = y0;
        *(ushort4*)(op + 4) = y1;
    }
}

// ---------------------------------------------------------------------------
extern "C" void kernel_launch(void* const* d_in, const int* in_sizes, int n_in,
                              void* d_out, int out_size, void* d_ws, size_t ws_size,
                              hipStream_t stream) {
    const void* hs = d_in[0];
    const void* Wq = d_in[1];
    const void* Wk = d_in[2];
    const void* Wv = d_in[3];
    const void* Wo = d_in[4];
    const void* gq = d_in[5];
    const void* bq = d_in[6];
    const void* gk = d_in[7];
    const void* bk = d_in[8];

    int* flag = (int*)d_ws;
    float* base = (float*)d_ws + 16;
    float* qpre = base;                                   // 4096*192
    float* kpre = qpre + (size_t)ROWS * HFD;              // 4096*192
    float* v    = kpre + (size_t)ROWS * HFD;              // 4096*1536 f32
    float* Sc   = v + (size_t)ROWS * HDV;                 // 384*256*128
    float* zc   = Sc + (size_t)Bc * Hc * NCH * D2c * DVc; // 384*256
    float* fend = zc + (size_t)Bc * Hc * NCH * D2c;
    unsigned short* hsb = (unsigned short*)fend;          // 4096*1536 bf16
    unsigned short* ob  = hsb;                            // alias (hsb dead before ob written)
    unsigned short* Wvt = hsb + (size_t)ROWS * DMc;       // 1536*1536 bf16 (N-major)
    unsigned short* Wot = Wvt + (size_t)DMc * HDV;        // 1536*1536 bf16 (N-major)

    probe_dtype<<<1, 256, 0, stream>>>((const unsigned short*)hs, flag);

    // bf16 prep
    conv_bf16<<<(ROWS * DMc / 4 + 255) / 256, 256, 0, stream>>>(hs, hsb, ROWS * DMc / 4, flag);
    convT_bf16<<<dim3(HDV / 64, DMc / 64), 256, 0, stream>>>(Wv, Wvt, DMc, HDV, flag);
    convT_bf16<<<dim3(DMc / 64, HDV / 64), 256, 0, stream>>>(Wo, Wot, HDV, DMc, flag);

    // v = hs @ Wv  (MFMA, f32 out)
    gemm_mfma_bt<<<dim3(HDV / 128, ROWS / 128), 256, 0, stream>>>(
        hsb, Wvt, v, ROWS, HDV, DMc, 0, flag);

    // q/k projections (small, VALU)
    dim3 blk2d(16, 16);
    gemm_tiled<<<dim3(HFD / 64, ROWS / 64), blk2d, 0, stream>>>(
        hs, Wq, qpre, ROWS, HFD, DMc, 1, 1, 0, 0, flag);
    gemm_tiled<<<dim3(HFD / 64, ROWS / 64), blk2d, 0, stream>>>(
        hs, Wk, kpre, ROWS, HFD, DMc, 1, 1, 0, 0, flag);
    ln_kernel<<<ROWS, HFD, 0, stream>>>(qpre, kpre, gq, bq, gk, bk, flag);

    chunk_state_kernel<<<Bc * Hc * NCH, 256, 0, stream>>>(kpre, v, Sc, zc);
    sprefix_kernel<<<dim3((D2c * DVc) / 256, Bc * Hc), 256, 0, stream>>>(Sc);
    zprefix_kernel<<<Bc * Hc, 256, 0, stream>>>(zc);
    chunk_out_kernel<<<Bc * Hc * NCH, 256, 0, stream>>>(qpre, kpre, v, Sc, zc, ob);

    // out = o @ Wo  (MFMA, flagged output dtype)
    gemm_mfma_bt<<<dim3(DMc / 128, ROWS / 128), 256, 0, stream>>>(
        ob, Wot, d_out, ROWS, DMc, HDV, 2, flag);
}

// Round 4
// 531.126 us; speedup vs baseline: 2.6692x; 1.8115x over previous
//
#include <hip/hip_runtime.h>
#include <hip/hip_bf16.h>
#include <math.h>

// Problem constants
#define Bc   2
#define Lc   2048
#define DMc  1536
#define Hc   12
#define FDc  16
#define DVc  128
#define D2c  256
#define CHK  128
#define NCH  16
#define ROWS (Bc*Lc)          // 4096
#define HFD  (Hc*FDc)         // 192
#define HDV  (Hc*DVc)         // 1536
#define NQK  (2*HFD)          // 384 fused q|k projection width

typedef __bf16 bf16x8 __attribute__((ext_vector_type(8)));
typedef float f32x4 __attribute__((ext_vector_type(4)));

__device__ __forceinline__ float bf2f(unsigned short u) {
    return __uint_as_float(((unsigned int)u) << 16);
}
__device__ __forceinline__ unsigned short f2bf(float v) {
    unsigned int u = __float_as_uint(v);
    unsigned int r = (u + 0x7FFFu + ((u >> 16) & 1u)) >> 16;
    return (unsigned short)r;
}
__device__ __forceinline__ float ldin(const void* p, size_t i, int isf32) {
    return isf32 ? ((const float*)p)[i] : bf2f(((const unsigned short*)p)[i]);
}
__device__ __forceinline__ float scrubf(float v) {
    return (fabsf(v) < 1e30f) ? v : 0.f;
}

#define GLL16(g, l) __builtin_amdgcn_global_load_lds( \
    (const __attribute__((address_space(1))) unsigned int*)(g), \
    (__attribute__((address_space(3))) unsigned int*)(l), 16, 0, 0)

// ---------------------------------------------------------------------------
// Dtype probe: writes flag 0 = bf16 data, 1 = f32 data.
// ---------------------------------------------------------------------------
__global__ void probe_dtype(const unsigned short* __restrict__ hs, int* __restrict__ flag) {
    const int tid = threadIdx.x;
    int sane = 0;
    for (int i = tid; i < 1024; i += 256) {
        unsigned short b = hs[2 * i];
        int e = (b >> 7) & 0xFF;
        if (e >= 97 && e <= 157) sane++;
    }
    __shared__ int tot;
    if (tid == 0) tot = 0;
    __syncthreads();
    atomicAdd(&tot, sane);
    __syncthreads();
    if (tid == 0) *flag = (tot >= 614) ? 0 : 1;
}

// ---------------------------------------------------------------------------
// Elementwise convert to bf16 (4 elems/thread).
// ---------------------------------------------------------------------------
__global__ __launch_bounds__(256) void conv_bf16(const void* __restrict__ X,
                                                 unsigned short* __restrict__ Y,
                                                 int n4, const int* __restrict__ flagp) {
    const int f = *flagp;
    int i = blockIdx.x * 256 + threadIdx.x;
    if (i >= n4) return;
    if (f) {
        float4 x = ((const float4*)X)[i];
        ushort4 y;
        y.x = f2bf(x.x); y.y = f2bf(x.y); y.z = f2bf(x.z); y.w = f2bf(x.w);
        ((ushort4*)Y)[i] = y;
    } else {
        ((ushort4*)Y)[i] = ((const ushort4*)X)[i];
    }
}

// ---------------------------------------------------------------------------
// Transpose + convert: Wt[n][k] = bf16(W[k][n]). rows = K extent, cols = N extent.
// grid = (cols/64, rows/64).
// ---------------------------------------------------------------------------
__global__ __launch_bounds__(256) void convT_bf16(const void* __restrict__ W,
                                                  unsigned short* __restrict__ Wt,
                                                  int rows, int cols,
                                                  const int* __restrict__ flagp) {
    const int f = *flagp;
    __shared__ float tile[64][65];
    const int t = threadIdx.x;
    const int bx = blockIdx.x * 64;  // n
    const int by = blockIdx.y * 64;  // k
#pragma unroll
    for (int u = 0; u < 16; u++) {
        int idx = t + u * 256;
        int r = idx >> 6, c = idx & 63;
        tile[r][c] = ldin(W, (size_t)(by + r) * cols + bx + c, f);
    }
    __syncthreads();
#pragma unroll
    for (int u = 0; u < 16; u++) {
        int idx = t + u * 256;
        int r = idx >> 6, c = idx & 63;   // r = n-local, c = k-local
        Wt[(size_t)(bx + r) * rows + by + c] = f2bf(tile[c][r]);
    }
}

// ---------------------------------------------------------------------------
// MFMA bf16 GEMM: C(MxN) = A(MxK) @ Bt(NxK)^T. 128x128 tile, 4 waves,
// each wave a 64x64 subtile of 4x4 16x16x32 MFMAs. global_load_lds staging.
// cMode: 0 = C f32, 1 = C bf16, 2 = flagged (f32 if flag else bf16).
// M,N % 128 == 0, K % 32 == 0.
// ---------------------------------------------------------------------------
__global__ __launch_bounds__(256) void gemm_mfma_bt(const unsigned short* __restrict__ A,
                                                    const unsigned short* __restrict__ Bt,
                                                    void* __restrict__ C,
                                                    int M, int N, int K,
                                                    int cMode, const int* __restrict__ flagp) {
    const int f = *flagp;
    const bool cF32 = (cMode == 0) || (cMode == 2 && f == 1);
    __shared__ __align__(16) unsigned short As[128 * 32];
    __shared__ __align__(16) unsigned short Bs[128 * 32];
    const int tid = threadIdx.x;
    const int wave = tid >> 6, lane = tid & 63;
    const int row0 = blockIdx.y * 128, col0 = blockIdx.x * 128;
    const int wrow = (wave >> 1) * 64, wcol = (wave & 1) * 64;
    const int mlane = lane & 15, quad = lane >> 4;

    const unsigned short* Ab = A + (size_t)row0 * K;
    const unsigned short* Bb = Bt + (size_t)col0 * K;
    const int r0 = tid >> 2;
    const int kc = (tid & 3) * 8;
    const size_t off0 = (size_t)r0 * K + kc;
    const size_t off1 = (size_t)(r0 + 64) * K + kc;
    char* AsW = (char*)As + wave * 1024;
    char* BsW = (char*)Bs + wave * 1024;

    f32x4 acc[4][4] = {};

    for (int k0 = 0; k0 < K; k0 += 32) {
        GLL16(Ab + off0 + k0, AsW);
        GLL16(Ab + off1 + k0, AsW + 4096);
        GLL16(Bb + off0 + k0, BsW);
        GLL16(Bb + off1 + k0, BsW + 4096);
        __syncthreads();
        bf16x8 a[4], b[4];
#pragma unroll
        for (int i = 0; i < 4; i++)
            a[i] = *(const bf16x8*)&As[(wrow + i * 16 + mlane) * 32 + quad * 8];
#pragma unroll
        for (int j = 0; j < 4; j++)
            b[j] = *(const bf16x8*)&Bs[(wcol + j * 16 + mlane) * 32 + quad * 8];
#pragma unroll
        for (int i = 0; i < 4; i++)
#pragma unroll
            for (int j = 0; j < 4; j++)
                acc[i][j] = __builtin_amdgcn_mfma_f32_16x16x32_bf16(a[i], b[j], acc[i][j], 0, 0, 0);
        __syncthreads();
    }

#pragma unroll
    for (int i = 0; i < 4; i++)
#pragma unroll
        for (int j = 0; j < 4; j++) {
            const int col = col0 + wcol + j * 16 + mlane;
#pragma unroll
            for (int r = 0; r < 4; r++) {
                const int row = row0 + wrow + i * 16 + quad * 4 + r;
                float vv = acc[i][j][r];
                if (cF32) ((float*)C)[(size_t)row * N + col] = vv;
                else      ((unsigned short*)C)[(size_t)row * N + col] = f2bf(vv);
            }
        }
}

// ---------------------------------------------------------------------------
// Fused LayerNorm: reads fused qk buffer (4096 x 384, q cols 0..191, k cols
// 192..383), writes qpre/kpre in (4096 x 192) layout.
// ---------------------------------------------------------------------------
__global__ __launch_bounds__(192) void ln_kernel(const float* __restrict__ qk,
                                                 float* __restrict__ q, float* __restrict__ k,
                                                 const void* __restrict__ gq,
                                                 const void* __restrict__ bq,
                                                 const void* __restrict__ gk,
                                                 const void* __restrict__ bk,
                                                 const int* __restrict__ flagp) {
    const int f = *flagp;
    const int row = blockIdx.x, t = threadIdx.x;
    float vq = qk[(size_t)row * NQK + t];
    float vk = qk[(size_t)row * NQK + HFD + t];
    float s[4] = {vq, vq * vq, vk, vk * vk};
    __shared__ float part[4][3];
    const int w = t >> 6, lane = t & 63;
#pragma unroll
    for (int i = 0; i < 4; i++) {
        float v = s[i];
        for (int off = 32; off; off >>= 1) v += __shfl_down(v, off);
        if (lane == 0) part[i][w] = v;
    }
    __syncthreads();
    float sq  = part[0][0] + part[0][1] + part[0][2];
    float sq2 = part[1][0] + part[1][1] + part[1][2];
    float sk  = part[2][0] + part[2][1] + part[2][2];
    float sk2 = part[3][0] + part[3][1] + part[3][2];
    const float inv = 1.0f / (float)HFD;
    float muq = sq * inv, muk = sk * inv;
    float varq = sq2 * inv - muq * muq;
    float vark = sk2 * inv - muk * muk;
    float oq = (vq - muq) * rsqrtf(varq + 1e-5f) * ldin(gq, t, f) + ldin(bq, t, f);
    float ok = (vk - muk) * rsqrtf(vark + 1e-5f) * ldin(gk, t, f) + ldin(bk, t, f);
    q[(size_t)row * HFD + t] = oq;
    k[(size_t)row * HFD + t] = ok;
}

// ---------------------------------------------------------------------------
// Per-chunk local state: Sc[d2][dv] = sum_c k2[c][d2]*v[c][dv], zc[d2]=sum_c k2[c][d2]
// ---------------------------------------------------------------------------
__global__ __launch_bounds__(256) void chunk_state_kernel(const float* __restrict__ kn,
                                                          const float* __restrict__ v,
                                                          float* __restrict__ Sc,
                                                          float* __restrict__ zc) {
    const int blk = blockIdx.x;
    const int n = blk & 15, bh = blk >> 4;
    const int h = bh % Hc, b = bh / Hc;
    const int row0 = b * Lc + n * CHK;
    const int tid = threadIdx.x;
    __shared__ float kcs[CHK * FDc];
    for (int u = tid; u < CHK * FDc; u += 256) {
        int c = u >> 4, ff = u & 15;
        kcs[u] = kn[(size_t)(row0 + c) * HFD + h * FDc + ff];
    }
    __syncthreads();
    const int i = tid >> 4, j = tid & 15;
    float4 acc[32];
#pragma unroll
    for (int d = 0; d < 32; d++) acc[d] = make_float4(0.f, 0.f, 0.f, 0.f);
    float zacc = 0.f;
    for (int c = 0; c < CHK; c++) {
        float sk = kcs[c * 16 + i] * kcs[c * 16 + j] * 0.25f;
        zacc += sk;
        const float4* vr = (const float4*)(v + (size_t)(row0 + c) * HDV + h * DVc);
#pragma unroll
        for (int d = 0; d < 32; d++) {
            float4 vv = vr[d];
            acc[d].x += sk * vv.x; acc[d].y += sk * vv.y;
            acc[d].z += sk * vv.z; acc[d].w += sk * vv.w;
        }
    }
    float4* outp = (float4*)(Sc + (size_t)blk * (D2c * DVc) + (size_t)tid * DVc);
#pragma unroll
    for (int d = 0; d < 32; d++) outp[d] = acc[d];
    zc[blk * D2c + tid] = zacc;
}

// ---------------------------------------------------------------------------
// Exclusive prefix over the 16 chunks (in place).
// ---------------------------------------------------------------------------
__global__ __launch_bounds__(256) void sprefix_kernel(float* __restrict__ S) {
    const int bh = blockIdx.y;
    const int elem = blockIdx.x * 256 + threadIdx.x;
    size_t base = (size_t)bh * NCH * (D2c * DVc) + elem;
    float a = 0.f;
#pragma unroll
    for (int n = 0; n < NCH; n++) {
        float t = S[base + (size_t)n * (D2c * DVc)];
        S[base + (size_t)n * (D2c * DVc)] = a;
        a += t;
    }
}

__global__ __launch_bounds__(256) void zprefix_kernel(float* __restrict__ z) {
    const int bh = blockIdx.x;
    size_t base = (size_t)bh * NCH * D2c + threadIdx.x;
    float a = 0.f;
#pragma unroll
    for (int n = 0; n < NCH; n++) {
        float t = z[base + (size_t)n * D2c];
        z[base + (size_t)n * D2c] = a;
        a += t;
    }
}

// ---------------------------------------------------------------------------
// Per-chunk output. o = (q2 @ Sstate + (A*tril) @ v) / (q2@z + rowsum(A) + eps)
// Output written as bf16 (feeds the MFMA out-projection).
// ---------------------------------------------------------------------------
__global__ __launch_bounds__(256) void chunk_out_kernel(const float* __restrict__ qn,
                                                        const float* __restrict__ kn,
                                                        const float* __restrict__ v,
                                                        const float* __restrict__ S,
                                                        const float* __restrict__ z,
                                                        unsigned short* __restrict__ o) {
    const int blk = blockIdx.x;
    const int n = blk & 15, bh = blk >> 4;
    const int h = bh % Hc, b = bh / Hc;
    const int row0 = b * Lc + n * CHK;
    const int tid = threadIdx.x;

    __shared__ __align__(16) float qcs[CHK * FDc];
    __shared__ __align__(16) unsigned char regionB[41984];
    __shared__ float denl[CHK];
    __shared__ float rs2[2][CHK];

    float* Stile = (float*)regionB;                          // [32*128]
    float* zl = (float*)(regionB + 16384);                   // [256]
    float* kcs = (float*)regionB;                            // [128*16]
    unsigned short* At = (unsigned short*)(regionB + 8192);  // [128*128] bf16 bits, e-major

    for (int u = tid; u < CHK * FDc; u += 256) {
        int c = u >> 4, ff = u & 15;
        qcs[u] = qn[(size_t)(row0 + c) * HFD + h * FDc + ff];
    }
    zl[tid] = z[(size_t)bh * (NCH * D2c) + n * D2c + tid];
    __syncthreads();

    const int ci = tid >> 4, dvi = tid & 15;
    const int c0 = ci * 8, dv0 = dvi * 8;
    float acc[8][8] = {};
    float den1[8] = {};
    const size_t Sbase = (size_t)blk * (D2c * DVc);

    for (int ti = 0; ti < 8; ti++) {
        for (int u = tid; u < 1024; u += 256)
            ((float4*)Stile)[u] = ((const float4*)(S + Sbase + (size_t)ti * 4096))[u];
        __syncthreads();
        for (int d2l = 0; d2l < 32; d2l++) {
            int d2 = ti * 32 + d2l;
            int i = d2 >> 4, j = d2 & 15;
            float zv = zl[d2];
            float4 s0 = *(const float4*)&Stile[d2l * 128 + dv0];
            float4 s1 = *(const float4*)&Stile[d2l * 128 + dv0 + 4];
#pragma unroll
            for (int cc = 0; cc < 8; cc++) {
                float q2v = qcs[(c0 + cc) * 16 + i] * qcs[(c0 + cc) * 16 + j] * 0.25f;
                den1[cc] += q2v * zv;
                acc[cc][0] += q2v * s0.x; acc[cc][1] += q2v * s0.y;
                acc[cc][2] += q2v * s0.z; acc[cc][3] += q2v * s0.w;
                acc[cc][4] += q2v * s1.x; acc[cc][5] += q2v * s1.y;
                acc[cc][6] += q2v * s1.z; acc[cc][7] += q2v * s1.w;
            }
        }
        __syncthreads();
    }
    if (dvi == 0) {
#pragma unroll
        for (int cc = 0; cc < 8; cc++) denl[c0 + cc] = den1[cc];
    }
    for (int u = tid; u < CHK * FDc; u += 256) {
        int c = u >> 4, ff = u & 15;
        kcs[u] = kn[(size_t)(row0 + c) * HFD + h * FDc + ff];
    }
    __syncthreads();

    {
        const int c = tid & 127, eb = tid >> 7;
        float qr[16];
#pragma unroll
        for (int ff = 0; ff < 16; ff++) qr[ff] = qcs[c * 16 + ff];
        float rs = 0.f;
        for (int ee = 0; ee < 64; ee++) {
            int e = eb * 64 + ee;
            float dot = 0.f;
#pragma unroll
            for (int ff = 0; ff < 16; ff++) dot += qr[ff] * kcs[e * 16 + ff];
            float a = (e <= c) ? dot * dot * 0.0625f : 0.f;
            rs += a;
            At[e * 128 + c] = f2bf(a);
        }
        rs2[eb][c] = rs;
    }
    __syncthreads();

    const float* vb = v + (size_t)row0 * HDV + h * DVc + dv0;
    for (int e = 0; e < CHK; e++) {
        const unsigned short* ap = At + e * 128 + c0;
        float4 v0 = *(const float4*)(vb + (size_t)e * HDV);
        float4 v1 = *(const float4*)(vb + (size_t)e * HDV + 4);
        float af[8];
#pragma unroll
        for (int cc = 0; cc < 8; cc++) af[cc] = bf2f(ap[cc]);
#pragma unroll
        for (int cc = 0; cc < 8; cc++) {
            acc[cc][0] += af[cc] * v0.x; acc[cc][1] += af[cc] * v0.y;
            acc[cc][2] += af[cc] * v0.z; acc[cc][3] += af[cc] * v0.w;
            acc[cc][4] += af[cc] * v1.x; acc[cc][5] += af[cc] * v1.y;
            acc[cc][6] += af[cc] * v1.z; acc[cc][7] += af[cc] * v1.w;
        }
    }

#pragma unroll
    for (int cc = 0; cc < 8; cc++) {
        float den = denl[c0 + cc] + rs2[0][c0 + cc] + rs2[1][c0 + cc] + 1e-12f;
        float r = 1.0f / den;
        ushort4 y0, y1;
        y0.x = f2bf(scrubf(acc[cc][0] * r)); y0.y = f2bf(scrubf(acc[cc][1] * r));
        y0.z = f2bf(scrubf(acc[cc][2] * r)); y0.w = f2bf(scrubf(acc[cc][3] * r));
        y1.x = f2bf(scrubf(acc[cc][4] * r)); y1.y = f2bf(scrubf(acc[cc][5] * r));
        y1.z = f2bf(scrubf(acc[cc][6] * r)); y1.w = f2bf(scrubf(acc[cc][7] * r));
        unsigned short* op = o + (size_t)(row0 + c0 + cc) * HDV + h * DVc + dv0;
        *(ushort4*)op       = y0;
        *(ushort4*)(op + 4) = y1;
    }
}

// ---------------------------------------------------------------------------
extern "C" void kernel_launch(void* const* d_in, const int* in_sizes, int n_in,
                              void* d_out, int out_size, void* d_ws, size_t ws_size,
                              hipStream_t stream) {
    const void* hs = d_in[0];
    const void* Wq = d_in[1];
    const void* Wk = d_in[2];
    const void* Wv = d_in[3];
    const void* Wo = d_in[4];
    const void* gq = d_in[5];
    const void* bq = d_in[6];
    const void* gk = d_in[7];
    const void* bk = d_in[8];

    int* flag = (int*)d_ws;
    float* base = (float*)d_ws + 16;
    float* qpre = base;                                   // 4096*192 f32
    float* kpre = qpre + (size_t)ROWS * HFD;              // 4096*192 f32
    float* v    = kpre + (size_t)ROWS * HFD;              // 4096*1536 f32
    float* Sc   = v + (size_t)ROWS * HDV;                 // 384*256*128 f32 (50 MB)
    float* zc   = Sc + (size_t)Bc * Hc * NCH * D2c * DVc; // 384*256 f32
    float* fend = zc + (size_t)Bc * Hc * NCH * D2c;
    unsigned short* hsb = (unsigned short*)fend;          // 4096*1536 bf16
    unsigned short* ob  = hsb;                            // alias (hsb dead before ob written)
    unsigned short* Wvt = hsb + (size_t)ROWS * DMc;       // 1536*1536 bf16 (N-major)
    unsigned short* Wot = Wvt + (size_t)DMc * HDV;        // 1536*1536 bf16 (N-major)
    // qk (4096*384 f32 = 6.3 MB) and Wqkt (384*1536 bf16 = 1.2 MB) alias the
    // Sc region: both are dead before chunk_state writes Sc.
    float* qk = Sc;
    unsigned short* Wqkt = (unsigned short*)(Sc + (size_t)ROWS * NQK);

    probe_dtype<<<1, 256, 0, stream>>>((const unsigned short*)hs, flag);

    // bf16 prep
    conv_bf16<<<(ROWS * DMc / 4 + 255) / 256, 256, 0, stream>>>(hs, hsb, ROWS * DMc / 4, flag);
    convT_bf16<<<dim3(HFD / 64, DMc / 64), 256, 0, stream>>>(Wq, Wqkt, DMc, HFD, flag);
    convT_bf16<<<dim3(HFD / 64, DMc / 64), 256, 0, stream>>>(Wk, Wqkt + (size_t)HFD * DMc, DMc, HFD, flag);
    convT_bf16<<<dim3(HDV / 64, DMc / 64), 256, 0, stream>>>(Wv, Wvt, DMc, HDV, flag);
    convT_bf16<<<dim3(DMc / 64, HDV / 64), 256, 0, stream>>>(Wo, Wot, HDV, DMc, flag);

    // qk = hs @ [Wq|Wk]  (MFMA, f32 out)
    gemm_mfma_bt<<<dim3(NQK / 128, ROWS / 128), 256, 0, stream>>>(
        hsb, Wqkt, qk, ROWS, NQK, DMc, 0, flag);
    // v = hs @ Wv  (MFMA, f32 out)
    gemm_mfma_bt<<<dim3(HDV / 128, ROWS / 128), 256, 0, stream>>>(
        hsb, Wvt, v, ROWS, HDV, DMc, 0, flag);

    ln_kernel<<<ROWS, HFD, 0, stream>>>(qk, qpre, kpre, gq, bq, gk, bk, flag);

    chunk_state_kernel<<<Bc * Hc * NCH, 256, 0, stream>>>(kpre, v, Sc, zc);
    sprefix_kernel<<<dim3((D2c * DVc) / 256, Bc * Hc), 256, 0, stream>>>(Sc);
    zprefix_kernel<<<Bc * Hc, 256, 0, stream>>>(zc);
    chunk_out_kernel<<<Bc * Hc * NCH, 256, 0, stream>>>(qpre, kpre, v, Sc, zc, ob);

    // out = o @ Wo  (MFMA, flagged output dtype)
    gemm_mfma_bt<<<dim3(DMc / 128, ROWS / 128), 256, 0, stream>>>(
        ob, Wot, d_out, ROWS, DMc, HDV, 2, flag);
}

// Round 6
// 415.765 us; speedup vs baseline: 3.4098x; 1.2775x over previous
//
#include <hip/hip_runtime.h>
#include <hip/hip_bf16.h>
#include <math.h>

// Problem constants
#define Bc   2
#define Lc   2048
#define DMc  1536
#define Hc   12
#define FDc  16
#define DVc  128
#define D2c  256
#define CHK  128
#define NCH  16
#define ROWS (Bc*Lc)          // 4096
#define HFD  (Hc*FDc)         // 192
#define HDV  (Hc*DVc)         // 1536
#define NQK  (2*HFD)          // 384 fused q|k projection width

typedef __bf16 bf16x8 __attribute__((ext_vector_type(8)));
typedef float f32x4 __attribute__((ext_vector_type(4)));

__device__ __forceinline__ float bf2f(unsigned short u) {
    return __uint_as_float(((unsigned int)u) << 16);
}
__device__ __forceinline__ unsigned short f2bf(float v) {
    unsigned int u = __float_as_uint(v);
    unsigned int r = (u + 0x7FFFu + ((u >> 16) & 1u)) >> 16;
    return (unsigned short)r;
}
__device__ __forceinline__ unsigned int pack2(unsigned short a, unsigned short b) {
    return (unsigned int)a | ((unsigned int)b << 16);
}
__device__ __forceinline__ float ldin(const void* p, size_t i, int isf32) {
    return isf32 ? ((const float*)p)[i] : bf2f(((const unsigned short*)p)[i]);
}
__device__ __forceinline__ float scrubf(float v) {
    return (fabsf(v) < 1e30f) ? v : 0.f;
}

#define GLL16(g, l) __builtin_amdgcn_global_load_lds( \
    (const __attribute__((address_space(1))) unsigned int*)(g), \
    (__attribute__((address_space(3))) unsigned int*)(l), 16, 0, 0)

// ---------------------------------------------------------------------------
// Dtype probe: writes flag 0 = bf16 data, 1 = f32 data.
// ---------------------------------------------------------------------------
__global__ void probe_dtype(const unsigned short* __restrict__ hs, int* __restrict__ flag) {
    const int tid = threadIdx.x;
    int sane = 0;
    for (int i = tid; i < 1024; i += 256) {
        unsigned short b = hs[2 * i];
        int e = (b >> 7) & 0xFF;
        if (e >= 97 && e <= 157) sane++;
    }
    __shared__ int tot;
    if (tid == 0) tot = 0;
    __syncthreads();
    atomicAdd(&tot, sane);
    __syncthreads();
    if (tid == 0) *flag = (tot >= 614) ? 0 : 1;
}

// ---------------------------------------------------------------------------
// Elementwise convert to bf16 (4 elems/thread).
// ---------------------------------------------------------------------------
__global__ __launch_bounds__(256) void conv_bf16(const void* __restrict__ X,
                                                 unsigned short* __restrict__ Y,
                                                 int n4, const int* __restrict__ flagp) {
    const int f = *flagp;
    int i = blockIdx.x * 256 + threadIdx.x;
    if (i >= n4) return;
    if (f) {
        float4 x = ((const float4*)X)[i];
        ushort4 y;
        y.x = f2bf(x.x); y.y = f2bf(x.y); y.z = f2bf(x.z); y.w = f2bf(x.w);
        ((ushort4*)Y)[i] = y;
    } else {
        ((ushort4*)Y)[i] = ((const ushort4*)X)[i];
    }
}

// ---------------------------------------------------------------------------
// Transpose + convert: Wt[n][k] = bf16(W[k][n]). rows = K extent, cols = N extent.
// ---------------------------------------------------------------------------
__global__ __launch_bounds__(256) void convT_bf16(const void* __restrict__ W,
                                                  unsigned short* __restrict__ Wt,
                                                  int rows, int cols,
                                                  const int* __restrict__ flagp) {
    const int f = *flagp;
    __shared__ float tile[64][65];
    const int t = threadIdx.x;
    const int bx = blockIdx.x * 64;  // n
    const int by = blockIdx.y * 64;  // k
#pragma unroll
    for (int u = 0; u < 16; u++) {
        int idx = t + u * 256;
        int r = idx >> 6, c = idx & 63;
        tile[r][c] = ldin(W, (size_t)(by + r) * cols + bx + c, f);
    }
    __syncthreads();
#pragma unroll
    for (int u = 0; u < 16; u++) {
        int idx = t + u * 256;
        int r = idx >> 6, c = idx & 63;
        Wt[(size_t)(bx + r) * rows + by + c] = f2bf(tile[c][r]);
    }
}

// ---------------------------------------------------------------------------
// MFMA bf16 GEMM: C(MxN) = A(MxK) @ Bt(NxK)^T. 128x128 tile, 4 waves.
// cMode: 0 = C f32, 1 = C bf16, 2 = flagged. Optional vTout: also store
// C^T as bf16 with layout [N][M] (for the V^T consumer).
// ---------------------------------------------------------------------------
__global__ __launch_bounds__(256) void gemm_mfma_bt(const unsigned short* __restrict__ A,
                                                    const unsigned short* __restrict__ Bt,
                                                    void* __restrict__ C,
                                                    int M, int N, int K,
                                                    int cMode, const int* __restrict__ flagp,
                                                    unsigned short* __restrict__ vTout) {
    const int f = *flagp;
    const bool cF32 = (cMode == 0) || (cMode == 2 && f == 1);
    __shared__ __align__(16) unsigned short As[128 * 32];
    __shared__ __align__(16) unsigned short Bs[128 * 32];
    const int tid = threadIdx.x;
    const int wave = tid >> 6, lane = tid & 63;
    const int row0 = blockIdx.y * 128, col0 = blockIdx.x * 128;
    const int wrow = (wave >> 1) * 64, wcol = (wave & 1) * 64;
    const int mlane = lane & 15, quad = lane >> 4;

    const unsigned short* Ab = A + (size_t)row0 * K;
    const unsigned short* Bb = Bt + (size_t)col0 * K;
    const int r0 = tid >> 2;
    const int kc = (tid & 3) * 8;
    const size_t off0 = (size_t)r0 * K + kc;
    const size_t off1 = (size_t)(r0 + 64) * K + kc;
    char* AsW = (char*)As + wave * 1024;
    char* BsW = (char*)Bs + wave * 1024;

    f32x4 acc[4][4] = {};

    for (int k0 = 0; k0 < K; k0 += 32) {
        GLL16(Ab + off0 + k0, AsW);
        GLL16(Ab + off1 + k0, AsW + 4096);
        GLL16(Bb + off0 + k0, BsW);
        GLL16(Bb + off1 + k0, BsW + 4096);
        __syncthreads();
        bf16x8 a[4], b[4];
#pragma unroll
        for (int i = 0; i < 4; i++)
            a[i] = *(const bf16x8*)&As[(wrow + i * 16 + mlane) * 32 + quad * 8];
#pragma unroll
        for (int j = 0; j < 4; j++)
            b[j] = *(const bf16x8*)&Bs[(wcol + j * 16 + mlane) * 32 + quad * 8];
#pragma unroll
        for (int i = 0; i < 4; i++)
#pragma unroll
            for (int j = 0; j < 4; j++)
                acc[i][j] = __builtin_amdgcn_mfma_f32_16x16x32_bf16(a[i], b[j], acc[i][j], 0, 0, 0);
        __syncthreads();
    }

#pragma unroll
    for (int i = 0; i < 4; i++)
#pragma unroll
        for (int j = 0; j < 4; j++) {
            const int col = col0 + wcol + j * 16 + mlane;
#pragma unroll
            for (int r = 0; r < 4; r++) {
                const int row = row0 + wrow + i * 16 + quad * 4 + r;
                float vv = acc[i][j][r];
                if (cF32) ((float*)C)[(size_t)row * N + col] = vv;
                else      ((unsigned short*)C)[(size_t)row * N + col] = f2bf(vv);
            }
            if (vTout) {
                ushort4 pk;
                pk.x = f2bf(acc[i][j][0]); pk.y = f2bf(acc[i][j][1]);
                pk.z = f2bf(acc[i][j][2]); pk.w = f2bf(acc[i][j][3]);
                *(ushort4*)(vTout + (size_t)col * M + row0 + wrow + i * 16 + quad * 4) = pk;
            }
        }
}

// ---------------------------------------------------------------------------
// Fused LayerNorm: reads fused qk (4096 x 384), writes qpre/kpre (4096 x 192).
// ---------------------------------------------------------------------------
__global__ __launch_bounds__(192) void ln_kernel(const float* __restrict__ qk,
                                                 float* __restrict__ q, float* __restrict__ k,
                                                 const void* __restrict__ gq,
                                                 const void* __restrict__ bq,
                                                 const void* __restrict__ gk,
                                                 const void* __restrict__ bk,
                                                 const int* __restrict__ flagp) {
    const int f = *flagp;
    const int row = blockIdx.x, t = threadIdx.x;
    float vq = qk[(size_t)row * NQK + t];
    float vk = qk[(size_t)row * NQK + HFD + t];
    float s[4] = {vq, vq * vq, vk, vk * vk};
    __shared__ float part[4][3];
    const int w = t >> 6, lane = t & 63;
#pragma unroll
    for (int i = 0; i < 4; i++) {
        float v = s[i];
        for (int off = 32; off; off >>= 1) v += __shfl_down(v, off);
        if (lane == 0) part[i][w] = v;
    }
    __syncthreads();
    float sq  = part[0][0] + part[0][1] + part[0][2];
    float sq2 = part[1][0] + part[1][1] + part[1][2];
    float sk  = part[2][0] + part[2][1] + part[2][2];
    float sk2 = part[3][0] + part[3][1] + part[3][2];
    const float inv = 1.0f / (float)HFD;
    float muq = sq * inv, muk = sk * inv;
    float varq = sq2 * inv - muq * muq;
    float vark = sk2 * inv - muk * muk;
    float oq = (vq - muq) * rsqrtf(varq + 1e-5f) * ldin(gq, t, f) + ldin(bq, t, f);
    float ok = (vk - muk) * rsqrtf(vark + 1e-5f) * ldin(gk, t, f) + ldin(bk, t, f);
    q[(size_t)row * HFD + t] = oq;
    k[(size_t)row * HFD + t] = ok;
}

// ---------------------------------------------------------------------------
// Per-chunk local state: Sc[d2][dv] = sum_c k2[c][d2]*v[c][dv], zc[d2]=sum_c k2
// ---------------------------------------------------------------------------
__global__ __launch_bounds__(256) void chunk_state_kernel(const float* __restrict__ kn,
                                                          const float* __restrict__ v,
                                                          float* __restrict__ Sc,
                                                          float* __restrict__ zc) {
    const int blk = blockIdx.x;
    const int n = blk & 15, bh = blk >> 4;
    const int h = bh % Hc, b = bh / Hc;
    const int row0 = b * Lc + n * CHK;
    const int tid = threadIdx.x;
    __shared__ float kcs[CHK * FDc];
    for (int u = tid; u < CHK * FDc; u += 256) {
        int c = u >> 4, ff = u & 15;
        kcs[u] = kn[(size_t)(row0 + c) * HFD + h * FDc + ff];
    }
    __syncthreads();
    const int i = tid >> 4, j = tid & 15;
    float4 acc[32];
#pragma unroll
    for (int d = 0; d < 32; d++) acc[d] = make_float4(0.f, 0.f, 0.f, 0.f);
    float zacc = 0.f;
    for (int c = 0; c < CHK; c++) {
        float sk = kcs[c * 16 + i] * kcs[c * 16 + j] * 0.25f;
        zacc += sk;
        const float4* vr = (const float4*)(v + (size_t)(row0 + c) * HDV + h * DVc);
#pragma unroll
        for (int d = 0; d < 32; d++) {
            float4 vv = vr[d];
            acc[d].x += sk * vv.x; acc[d].y += sk * vv.y;
            acc[d].z += sk * vv.z; acc[d].w += sk * vv.w;
        }
    }
    float4* outp = (float4*)(Sc + (size_t)blk * (D2c * DVc) + (size_t)tid * DVc);
#pragma unroll
    for (int d = 0; d < 32; d++) outp[d] = acc[d];
    zc[blk * D2c + tid] = zacc;
}

// ---------------------------------------------------------------------------
// Exclusive prefix over 16 chunks + transpose + bf16: St[bh][n][dv][d2].
// grid (16 d2-tiles, 24 bh), 256 threads. Tile = 16 d2 x 128 dv.
// ---------------------------------------------------------------------------
__global__ __launch_bounds__(256) void sprefix2_kernel(const float* __restrict__ Sc,
                                                       unsigned short* __restrict__ St) {
    const int bh = blockIdx.y;
    const int d2base = blockIdx.x * 16;
    const int tid = threadIdx.x;
    __shared__ float T[16][128];
    const int d2l = tid >> 4, dv8 = (tid & 15) * 8;
    float pre[8] = {};
    for (int n = 0; n < NCH; n++) {
        const float* src = Sc + ((size_t)(bh * NCH + n) * D2c + d2base + d2l) * DVc + dv8;
        float4 c0 = *(const float4*)src;
        float4 c1 = *(const float4*)(src + 4);
        *(float4*)&T[d2l][dv8]     = make_float4(pre[0], pre[1], pre[2], pre[3]);
        *(float4*)&T[d2l][dv8 + 4] = make_float4(pre[4], pre[5], pre[6], pre[7]);
        __syncthreads();
        {
            int dv = tid >> 1, ch = tid & 1;
            uint4 pk;
            pk.x = pack2(f2bf(T[ch * 8 + 0][dv]), f2bf(T[ch * 8 + 1][dv]));
            pk.y = pack2(f2bf(T[ch * 8 + 2][dv]), f2bf(T[ch * 8 + 3][dv]));
            pk.z = pack2(f2bf(T[ch * 8 + 4][dv]), f2bf(T[ch * 8 + 5][dv]));
            pk.w = pack2(f2bf(T[ch * 8 + 6][dv]), f2bf(T[ch * 8 + 7][dv]));
            *(uint4*)(St + ((size_t)(bh * NCH + n) * DVc + dv) * D2c + d2base + ch * 8) = pk;
        }
        pre[0] += c0.x; pre[1] += c0.y; pre[2] += c0.z; pre[3] += c0.w;
        pre[4] += c1.x; pre[5] += c1.y; pre[6] += c1.z; pre[7] += c1.w;
        __syncthreads();
    }
}

__global__ __launch_bounds__(256) void zprefix_kernel(float* __restrict__ z) {
    const int bh = blockIdx.x;
    size_t base = (size_t)bh * NCH * D2c + threadIdx.x;
    float a = 0.f;
#pragma unroll
    for (int n = 0; n < NCH; n++) {
        float t = z[base + (size_t)n * D2c];
        z[base + (size_t)n * D2c] = a;
        a += t;
    }
}

// ---------------------------------------------------------------------------
// MFMA chunk output. Per (bh, n) block:
//   num1 = Q2 @ S_prefix (via St bf16 [dv][d2]),  den1 = Q2 . z  (f32, fused)
//   P    = Q @ K^T (zero-padded K=32 MFMA), A = tril(P^2/16) -> LDS bf16
//   num2 = A @ V (via vT bf16 [dv][seq]),    den2 = rowsum(A)
//   o    = (num1+num2) / (den1+den2+eps)  -> bf16 row-major [4096][1536]
// ---------------------------------------------------------------------------
__global__ __launch_bounds__(256) void chunk_out_mfma(const float* __restrict__ qn,
                                                      const float* __restrict__ kn,
                                                      const unsigned short* __restrict__ St,
                                                      const float* __restrict__ z,
                                                      const unsigned short* __restrict__ vT,
                                                      unsigned short* __restrict__ o) {
    const int blk = blockIdx.x;
    const int n = blk & 15, bh = blk >> 4;
    const int h = bh % Hc, b = bh / Hc;
    const int row0 = b * Lc + n * CHK;
    const int tid = threadIdx.x;
    const int wave = tid >> 6, lane = tid & 63;
    const int mlane = lane & 15, quad = lane >> 4;
    const int wrow = (wave >> 1) * 64, wcol = (wave & 1) * 64;

    __shared__ __align__(16) unsigned char lds[61952];
    float* Qs   = (float*)lds;                           // [128][16] f32   8192
    float* zs   = (float*)(lds + 8192);                  // [256]           1024
    float* denp = (float*)(lds + 9216);                  // [2][128]        1024
    float* dinv = (float*)(lds + 10240);                 // [128]           512
    unsigned char* U = lds + 10752;
    unsigned short* Q2s = (unsigned short*)U;            // [128][40] bf16  10240
    unsigned short* Sts = (unsigned short*)(U + 10240);  // [128][40] bf16  10240
    unsigned short* Kb  = (unsigned short*)U;            // [128][32] bf16  8192
    unsigned short* Qb  = (unsigned short*)(U + 8192);   // [128][32] bf16  8192
    unsigned short* At  = (unsigned short*)(U + 16384);  // [128][136] bf16 34816
    unsigned short* Vs  = (unsigned short*)U;            // [128][40] bf16  10240

    // ---- load Qs (f32, FULL 16 floats per row: 2x float4 per thread) and zs ----
    {
        int r = tid >> 1, hf = tid & 1;
        const float4* src = (const float4*)(qn + (size_t)(row0 + r) * HFD + h * FDc + hf * 8);
        *(float4*)(Qs + r * 16 + hf * 8)     = src[0];
        *(float4*)(Qs + r * 16 + hf * 8 + 4) = src[1];
        if (tid < 64)
            ((float4*)zs)[tid] = ((const float4*)(z + ((size_t)bh * NCH + n) * D2c))[tid];
    }
    __syncthreads();

    const int qc = tid >> 1, qhalf = tid & 1;
    float qr[16];
#pragma unroll
    for (int ff = 0; ff < 16; ff++) qr[ff] = Qs[qc * 16 + ff];

    f32x4 acc[4][4] = {};
    float den1 = 0.f;
    const unsigned short* Stb = St + ((size_t)bh * NCH + n) * ((size_t)D2c * DVc);

    // ---- num1: K = 256 over d2 in 32-slabs ----
    for (int k0 = 0; k0 < 256; k0 += 32) {
        {
            unsigned short pk[16];
#pragma unroll
            for (int kk = 0; kk < 16; kk++) {
                int d2 = k0 + qhalf * 16 + kk;
                float val = qr[d2 >> 4] * qr[d2 & 15] * 0.25f;
                den1 += val * zs[d2];
                pk[kk] = f2bf(val);
            }
            uint4 w0, w1;
            w0.x = pack2(pk[0], pk[1]);  w0.y = pack2(pk[2], pk[3]);
            w0.z = pack2(pk[4], pk[5]);  w0.w = pack2(pk[6], pk[7]);
            w1.x = pack2(pk[8], pk[9]);  w1.y = pack2(pk[10], pk[11]);
            w1.z = pack2(pk[12], pk[13]); w1.w = pack2(pk[14], pk[15]);
            *(uint4*)(Q2s + qc * 40 + qhalf * 16) = w0;
            *(uint4*)(Q2s + qc * 40 + qhalf * 16 + 8) = w1;
        }
        {
            int r = tid >> 1, hf = tid & 1;
            const uint4* g = (const uint4*)(Stb + (size_t)r * D2c + k0 + hf * 16);
            uint4 d0 = g[0], d1 = g[1];
            *(uint4*)(Sts + r * 40 + hf * 16) = d0;
            *(uint4*)(Sts + r * 40 + hf * 16 + 8) = d1;
        }
        __syncthreads();
        bf16x8 a[4], bfr[4];
#pragma unroll
        for (int i = 0; i < 4; i++)
            a[i] = *(const bf16x8*)(Q2s + (wrow + i * 16 + mlane) * 40 + quad * 8);
#pragma unroll
        for (int j = 0; j < 4; j++)
            bfr[j] = *(const bf16x8*)(Sts + (wcol + j * 16 + mlane) * 40 + quad * 8);
#pragma unroll
        for (int i = 0; i < 4; i++)
#pragma unroll
            for (int j = 0; j < 4; j++)
                acc[i][j] = __builtin_amdgcn_mfma_f32_16x16x32_bf16(a[i], bfr[j], acc[i][j], 0, 0, 0);
        __syncthreads();
    }
    denp[qhalf * 128 + qc] = den1;

    // ---- build Qb, Kb zero-padded [128][32] ----
    {
        int r = tid >> 1, hf = tid & 1;
        if (hf == 0) {
            unsigned short pq[16], pkk[16];
#pragma unroll
            for (int ff = 0; ff < 16; ff++) pq[ff] = f2bf(Qs[r * 16 + ff]);
            const float* kg = kn + (size_t)(row0 + r) * HFD + h * FDc;
#pragma unroll
            for (int ff = 0; ff < 16; ff++) pkk[ff] = f2bf(kg[ff]);
            uint4 w;
            w.x = pack2(pq[0], pq[1]);  w.y = pack2(pq[2], pq[3]);
            w.z = pack2(pq[4], pq[5]);  w.w = pack2(pq[6], pq[7]);
            *(uint4*)(Qb + r * 32) = w;
            w.x = pack2(pq[8], pq[9]);  w.y = pack2(pq[10], pq[11]);
            w.z = pack2(pq[12], pq[13]); w.w = pack2(pq[14], pq[15]);
            *(uint4*)(Qb + r * 32 + 8) = w;
            w.x = pack2(pkk[0], pkk[1]);  w.y = pack2(pkk[2], pkk[3]);
            w.z = pack2(pkk[4], pkk[5]);  w.w = pack2(pkk[6], pkk[7]);
            *(uint4*)(Kb + r * 32) = w;
            w.x = pack2(pkk[8], pkk[9]);  w.y = pack2(pkk[10], pkk[11]);
            w.z = pack2(pkk[12], pkk[13]); w.w = pack2(pkk[14], pkk[15]);
            *(uint4*)(Kb + r * 32 + 8) = w;
        } else {
            uint4 zz = make_uint4(0, 0, 0, 0);
            *(uint4*)(Qb + r * 32 + 16) = zz;
            *(uint4*)(Qb + r * 32 + 24) = zz;
            *(uint4*)(Kb + r * 32 + 16) = zz;
            *(uint4*)(Kb + r * 32 + 24) = zz;
        }
    }
    __syncthreads();

    // ---- P = Q @ K^T, A = tril(P^2/16) ----
    {
        f32x4 pacc[4][4] = {};
        bf16x8 a[4], bfr[4];
#pragma unroll
        for (int i = 0; i < 4; i++)
            a[i] = *(const bf16x8*)(Qb + (wrow + i * 16 + mlane) * 32 + quad * 8);
#pragma unroll
        for (int j = 0; j < 4; j++)
            bfr[j] = *(const bf16x8*)(Kb + (wcol + j * 16 + mlane) * 32 + quad * 8);
#pragma unroll
        for (int i = 0; i < 4; i++)
#pragma unroll
            for (int j = 0; j < 4; j++)
                pacc[i][j] = __builtin_amdgcn_mfma_f32_16x16x32_bf16(a[i], bfr[j], pacc[i][j], 0, 0, 0);
#pragma unroll
        for (int i = 0; i < 4; i++)
#pragma unroll
            for (int j = 0; j < 4; j++) {
                int e = wcol + j * 16 + mlane;
#pragma unroll
                for (int r = 0; r < 4; r++) {
                    int c = wrow + i * 16 + quad * 4 + r;
                    float p = pacc[i][j][r];
                    float aval = (e <= c) ? p * p * 0.0625f : 0.f;
                    At[c * 136 + e] = f2bf(aval);
                }
            }
    }
    __syncthreads();

    // ---- dinv[c] = 1/(den1 + rowsum(A) + eps) ----
    if (tid < 128) {
        float rs = 0.f;
#pragma unroll
        for (int e8 = 0; e8 < 128; e8 += 8) {
            bf16x8 v8 = *(const bf16x8*)(At + tid * 136 + e8);
#pragma unroll
            for (int u = 0; u < 8; u++) rs += (float)v8[u];
        }
        dinv[tid] = 1.0f / (denp[tid] + denp[128 + tid] + rs + 1e-12f);
    }

    // ---- num2: A @ V, K = 128 over e in 32-slabs ----
    for (int e0 = 0; e0 < 128; e0 += 32) {
        {
            int r = tid >> 1, hf = tid & 1;
            const uint4* g = (const uint4*)(vT + (size_t)(h * 128 + r) * ROWS + row0 + e0 + hf * 16);
            uint4 d0 = g[0], d1 = g[1];
            *(uint4*)(Vs + r * 40 + hf * 16) = d0;
            *(uint4*)(Vs + r * 40 + hf * 16 + 8) = d1;
        }
        __syncthreads();
        bf16x8 a[4], bfr[4];
#pragma unroll
        for (int i = 0; i < 4; i++)
            a[i] = *(const bf16x8*)(At + (wrow + i * 16 + mlane) * 136 + e0 + quad * 8);
#pragma unroll
        for (int j = 0; j < 4; j++)
            bfr[j] = *(const bf16x8*)(Vs + (wcol + j * 16 + mlane) * 40 + quad * 8);
#pragma unroll
        for (int i = 0; i < 4; i++)
#pragma unroll
            for (int j = 0; j < 4; j++)
                acc[i][j] = __builtin_amdgcn_mfma_f32_16x16x32_bf16(a[i], bfr[j], acc[i][j], 0, 0, 0);
        __syncthreads();
    }

    // ---- epilogue ----
#pragma unroll
    for (int i = 0; i < 4; i++)
#pragma unroll
        for (int j = 0; j < 4; j++) {
            int col = h * 128 + wcol + j * 16 + mlane;
#pragma unroll
            for (int r = 0; r < 4; r++) {
                int c = wrow + i * 16 + quad * 4 + r;
                o[(size_t)(row0 + c) * HDV + col] = f2bf(acc[i][j][r] * dinv[c]);
            }
        }
}

// ---------------------------------------------------------------------------
extern "C" void kernel_launch(void* const* d_in, const int* in_sizes, int n_in,
                              void* d_out, int out_size, void* d_ws, size_t ws_size,
                              hipStream_t stream) {
    const void* hs = d_in[0];
    const void* Wq = d_in[1];
    const void* Wk = d_in[2];
    const void* Wv = d_in[3];
    const void* Wo = d_in[4];
    const void* gq = d_in[5];
    const void* bq = d_in[6];
    const void* gk = d_in[7];
    const void* bk = d_in[8];

    int* flag = (int*)d_ws;
    float* base = (float*)d_ws + 16;
    float* qpre = base;                                   // 4096*192 f32
    float* kpre = qpre + (size_t)ROWS * HFD;              // 4096*192 f32
    float* v    = kpre + (size_t)ROWS * HFD;              // 4096*1536 f32 (25.2 MB)
    float* Sc   = v + (size_t)ROWS * HDV;                 // 384*256*128 f32 (50 MB)
    float* zc   = Sc + (size_t)Bc * Hc * NCH * D2c * DVc; // 384*256 f32
    float* fend = zc + (size_t)Bc * Hc * NCH * D2c;
    unsigned short* hsb = (unsigned short*)fend;          // 4096*1536 bf16
    unsigned short* ob  = hsb;                            // alias (hsb dead before ob)
    unsigned short* Wvt = hsb + (size_t)ROWS * DMc;       // 1536*1536 bf16
    unsigned short* Wot = Wvt + (size_t)DMc * HDV;        // 1536*1536 bf16
    unsigned short* vT  = Wot + (size_t)HDV * DMc;        // 1536*4096 bf16 (12.6 MB)
    // aliases into Sc region (dead before chunk_state writes Sc):
    float* qk = Sc;                                       // 4096*384 f32
    unsigned short* Wqkt = (unsigned short*)(Sc + (size_t)ROWS * NQK);  // 384*1536 bf16
    // St (bf16 state, transposed) aliases v: v dead after chunk_state.
    unsigned short* St = (unsigned short*)v;              // 24*16*128*256 bf16 = 25.2 MB

    probe_dtype<<<1, 256, 0, stream>>>((const unsigned short*)hs, flag);

    // bf16 prep
    conv_bf16<<<(ROWS * DMc / 4 + 255) / 256, 256, 0, stream>>>(hs, hsb, ROWS * DMc / 4, flag);
    convT_bf16<<<dim3(HFD / 64, DMc / 64), 256, 0, stream>>>(Wq, Wqkt, DMc, HFD, flag);
    convT_bf16<<<dim3(HFD / 64, DMc / 64), 256, 0, stream>>>(Wk, Wqkt + (size_t)HFD * DMc, DMc, HFD, flag);
    convT_bf16<<<dim3(HDV / 64, DMc / 64), 256, 0, stream>>>(Wv, Wvt, DMc, HDV, flag);
    convT_bf16<<<dim3(DMc / 64, HDV / 64), 256, 0, stream>>>(Wo, Wot, HDV, DMc, flag);

    // qk = hs @ [Wq|Wk]
    gemm_mfma_bt<<<dim3(NQK / 128, ROWS / 128), 256, 0, stream>>>(
        hsb, Wqkt, qk, ROWS, NQK, DMc, 0, flag, nullptr);
    // v = hs @ Wv (also writes vT bf16)
    gemm_mfma_bt<<<dim3(HDV / 128, ROWS / 128), 256, 0, stream>>>(
        hsb, Wvt, v, ROWS, HDV, DMc, 0, flag, vT);

    ln_kernel<<<ROWS, HFD, 0, stream>>>(qk, qpre, kpre, gq, bq, gk, bk, flag);

    chunk_state_kernel<<<Bc * Hc * NCH, 256, 0, stream>>>(kpre, v, Sc, zc);
    sprefix2_kernel<<<dim3(16, Bc * Hc), 256, 0, stream>>>(Sc, St);
    zprefix_kernel<<<Bc * Hc, 256, 0, stream>>>(zc);
    chunk_out_mfma<<<Bc * Hc * NCH, 256, 0, stream>>>(qpre, kpre, St, zc, vT, ob);

    // out = o @ Wo
    gemm_mfma_bt<<<dim3(DMc / 128, ROWS / 128), 256, 0, stream>>>(
        ob, Wot, d_out, ROWS, DMc, HDV, 2, flag, nullptr);
}

// Round 7
// 354.189 us; speedup vs baseline: 4.0026x; 1.1738x over previous
//
#include <hip/hip_runtime.h>
#include <hip/hip_bf16.h>
#include <math.h>

// Problem constants
#define Bc   2
#define Lc   2048
#define DMc  1536
#define Hc   12
#define FDc  16
#define DVc  128
#define D2c  256
#define CHK  128
#define NCH  16
#define ROWS (Bc*Lc)          // 4096
#define HFD  (Hc*FDc)         // 192
#define HDV  (Hc*DVc)         // 1536
#define NQK  (2*HFD)          // 384 fused q|k projection width

typedef __bf16 bf16x8 __attribute__((ext_vector_type(8)));
typedef float f32x4 __attribute__((ext_vector_type(4)));

__device__ __forceinline__ float bf2f(unsigned short u) {
    return __uint_as_float(((unsigned int)u) << 16);
}
__device__ __forceinline__ unsigned short f2bf(float v) {
    unsigned int u = __float_as_uint(v);
    unsigned int r = (u + 0x7FFFu + ((u >> 16) & 1u)) >> 16;
    return (unsigned short)r;
}
__device__ __forceinline__ unsigned int pack2(unsigned short a, unsigned short b) {
    return (unsigned int)a | ((unsigned int)b << 16);
}
__device__ __forceinline__ float ldin(const void* p, size_t i, int isf32) {
    return isf32 ? ((const float*)p)[i] : bf2f(((const unsigned short*)p)[i]);
}
__device__ __forceinline__ float scrubf(float v) {
    return (fabsf(v) < 1e30f) ? v : 0.f;
}

#define GLL16(g, l) __builtin_amdgcn_global_load_lds( \
    (const __attribute__((address_space(1))) unsigned int*)(g), \
    (__attribute__((address_space(3))) unsigned int*)(l), 16, 0, 0)

// ---------------------------------------------------------------------------
// Dtype probe: writes flag 0 = bf16 data, 1 = f32 data.
// ---------------------------------------------------------------------------
__global__ void probe_dtype(const unsigned short* __restrict__ hs, int* __restrict__ flag) {
    const int tid = threadIdx.x;
    int sane = 0;
    for (int i = tid; i < 1024; i += 256) {
        unsigned short b = hs[2 * i];
        int e = (b >> 7) & 0xFF;
        if (e >= 97 && e <= 157) sane++;
    }
    __shared__ int tot;
    if (tid == 0) tot = 0;
    __syncthreads();
    atomicAdd(&tot, sane);
    __syncthreads();
    if (tid == 0) *flag = (tot >= 614) ? 0 : 1;
}

// ---------------------------------------------------------------------------
// Elementwise convert to bf16 (4 elems/thread).
// ---------------------------------------------------------------------------
__global__ __launch_bounds__(256) void conv_bf16(const void* __restrict__ X,
                                                 unsigned short* __restrict__ Y,
                                                 int n4, const int* __restrict__ flagp) {
    const int f = *flagp;
    int i = blockIdx.x * 256 + threadIdx.x;
    if (i >= n4) return;
    if (f) {
        float4 x = ((const float4*)X)[i];
        ushort4 y;
        y.x = f2bf(x.x); y.y = f2bf(x.y); y.z = f2bf(x.z); y.w = f2bf(x.w);
        ((ushort4*)Y)[i] = y;
    } else {
        ((ushort4*)Y)[i] = ((const ushort4*)X)[i];
    }
}

// ---------------------------------------------------------------------------
// Transpose + convert: Wt[n][k] = bf16(W[k][n]). rows = K extent, cols = N extent.
// ---------------------------------------------------------------------------
__global__ __launch_bounds__(256) void convT_bf16(const void* __restrict__ W,
                                                  unsigned short* __restrict__ Wt,
                                                  int rows, int cols,
                                                  const int* __restrict__ flagp) {
    const int f = *flagp;
    __shared__ float tile[64][65];
    const int t = threadIdx.x;
    const int bx = blockIdx.x * 64;  // n
    const int by = blockIdx.y * 64;  // k
#pragma unroll
    for (int u = 0; u < 16; u++) {
        int idx = t + u * 256;
        int r = idx >> 6, c = idx & 63;
        tile[r][c] = ldin(W, (size_t)(by + r) * cols + bx + c, f);
    }
    __syncthreads();
#pragma unroll
    for (int u = 0; u < 16; u++) {
        int idx = t + u * 256;
        int r = idx >> 6, c = idx & 63;
        Wt[(size_t)(bx + r) * rows + by + c] = f2bf(tile[c][r]);
    }
}

// ---------------------------------------------------------------------------
// MFMA bf16 GEMM: C(MxN) = A(MxK) @ Bt(NxK)^T. 128x128 tile, 4 waves.
// cMode: 0 = C f32, 1 = C bf16, 2 = flagged, 3 = no C store (vTout only).
// Optional vTout: store C^T bf16 [N][M].
// ---------------------------------------------------------------------------
__global__ __launch_bounds__(256) void gemm_mfma_bt(const unsigned short* __restrict__ A,
                                                    const unsigned short* __restrict__ Bt,
                                                    void* __restrict__ C,
                                                    int M, int N, int K,
                                                    int cMode, const int* __restrict__ flagp,
                                                    unsigned short* __restrict__ vTout) {
    const int f = *flagp;
    const bool writeC = (cMode != 3);
    const bool cF32 = (cMode == 0) || (cMode == 2 && f == 1);
    __shared__ __align__(16) unsigned short As[128 * 32];
    __shared__ __align__(16) unsigned short Bs[128 * 32];
    const int tid = threadIdx.x;
    const int wave = tid >> 6, lane = tid & 63;
    const int row0 = blockIdx.y * 128, col0 = blockIdx.x * 128;
    const int wrow = (wave >> 1) * 64, wcol = (wave & 1) * 64;
    const int mlane = lane & 15, quad = lane >> 4;

    const unsigned short* Ab = A + (size_t)row0 * K;
    const unsigned short* Bb = Bt + (size_t)col0 * K;
    const int r0 = tid >> 2;
    const int kc = (tid & 3) * 8;
    const size_t off0 = (size_t)r0 * K + kc;
    const size_t off1 = (size_t)(r0 + 64) * K + kc;
    char* AsW = (char*)As + wave * 1024;
    char* BsW = (char*)Bs + wave * 1024;

    f32x4 acc[4][4] = {};

    for (int k0 = 0; k0 < K; k0 += 32) {
        GLL16(Ab + off0 + k0, AsW);
        GLL16(Ab + off1 + k0, AsW + 4096);
        GLL16(Bb + off0 + k0, BsW);
        GLL16(Bb + off1 + k0, BsW + 4096);
        __syncthreads();
        bf16x8 a[4], b[4];
#pragma unroll
        for (int i = 0; i < 4; i++)
            a[i] = *(const bf16x8*)&As[(wrow + i * 16 + mlane) * 32 + quad * 8];
#pragma unroll
        for (int j = 0; j < 4; j++)
            b[j] = *(const bf16x8*)&Bs[(wcol + j * 16 + mlane) * 32 + quad * 8];
#pragma unroll
        for (int i = 0; i < 4; i++)
#pragma unroll
            for (int j = 0; j < 4; j++)
                acc[i][j] = __builtin_amdgcn_mfma_f32_16x16x32_bf16(a[i], b[j], acc[i][j], 0, 0, 0);
        __syncthreads();
    }

#pragma unroll
    for (int i = 0; i < 4; i++)
#pragma unroll
        for (int j = 0; j < 4; j++) {
            const int col = col0 + wcol + j * 16 + mlane;
            if (writeC) {
#pragma unroll
                for (int r = 0; r < 4; r++) {
                    const int row = row0 + wrow + i * 16 + quad * 4 + r;
                    float vv = acc[i][j][r];
                    if (cF32) ((float*)C)[(size_t)row * N + col] = vv;
                    else      ((unsigned short*)C)[(size_t)row * N + col] = f2bf(vv);
                }
            }
            if (vTout) {
                ushort4 pk;
                pk.x = f2bf(acc[i][j][0]); pk.y = f2bf(acc[i][j][1]);
                pk.z = f2bf(acc[i][j][2]); pk.w = f2bf(acc[i][j][3]);
                *(ushort4*)(vTout + (size_t)col * M + row0 + wrow + i * 16 + quad * 4) = pk;
            }
        }
}

// ---------------------------------------------------------------------------
// Fused LayerNorm: reads fused qk (4096 x 384), writes qpre/kpre (4096 x 192).
// ---------------------------------------------------------------------------
__global__ __launch_bounds__(192) void ln_kernel(const float* __restrict__ qk,
                                                 float* __restrict__ q, float* __restrict__ k,
                                                 const void* __restrict__ gq,
                                                 const void* __restrict__ bq,
                                                 const void* __restrict__ gk,
                                                 const void* __restrict__ bk,
                                                 const int* __restrict__ flagp) {
    const int f = *flagp;
    const int row = blockIdx.x, t = threadIdx.x;
    float vq = qk[(size_t)row * NQK + t];
    float vk = qk[(size_t)row * NQK + HFD + t];
    float s[4] = {vq, vq * vq, vk, vk * vk};
    __shared__ float part[4][3];
    const int w = t >> 6, lane = t & 63;
#pragma unroll
    for (int i = 0; i < 4; i++) {
        float v = s[i];
        for (int off = 32; off; off >>= 1) v += __shfl_down(v, off);
        if (lane == 0) part[i][w] = v;
    }
    __syncthreads();
    float sq  = part[0][0] + part[0][1] + part[0][2];
    float sq2 = part[1][0] + part[1][1] + part[1][2];
    float sk  = part[2][0] + part[2][1] + part[2][2];
    float sk2 = part[3][0] + part[3][1] + part[3][2];
    const float inv = 1.0f / (float)HFD;
    float muq = sq * inv, muk = sk * inv;
    float varq = sq2 * inv - muq * muq;
    float vark = sk2 * inv - muk * muk;
    float oq = (vq - muq) * rsqrtf(varq + 1e-5f) * ldin(gq, t, f) + ldin(bq, t, f);
    float ok = (vk - muk) * rsqrtf(vark + 1e-5f) * ldin(gk, t, f) + ldin(bk, t, f);
    q[(size_t)row * HFD + t] = oq;
    k[(size_t)row * HFD + t] = ok;
}

// ---------------------------------------------------------------------------
// Fused chunk-state + exclusive prefix + z prefix, MFMA.
// grid = (16 d2-tiles, 24 bh), 256 threads (4 waves).
// Block owns d2 range [bx*16, bx*16+16) x all 128 dv for one bh; iterates the
// 16 chunks keeping the running S-prefix in MFMA f32 accumulators and writing
// the EXCLUSIVE prefix as bf16 St[bh][n][t][dv][16] before each chunk update.
// Also maintains z exclusive prefix (f32) -> zc[bh][n][256].
// i index of this block's d2 = bx (uniform); j = d2l.
// ---------------------------------------------------------------------------
__global__ __launch_bounds__(256) void state_prefix_mfma(const float* __restrict__ kn,
                                                         const unsigned short* __restrict__ vT,
                                                         unsigned short* __restrict__ St,
                                                         float* __restrict__ zc) {
    const int bx = blockIdx.x;          // d2 tile = i index
    const int bh = blockIdx.y;
    const int h = bh % Hc, b = bh / Hc;
    const int t0 = bx * 16;
    const int tid = threadIdx.x;
    const int wave = tid >> 6, lane = tid & 63;
    const int mlane = lane & 15, quad = lane >> 4;

    __shared__ __align__(16) float kcs[CHK * FDc];          // [c][16] f32, 8 KB
    __shared__ __align__(16) unsigned short K2t[16 * 136];  // [d2l][c pad], 4.25 KB
    __shared__ float zp[16][17];
    __shared__ float zpre[16];
    if (tid < 16) zpre[tid] = 0.f;

    f32x4 acc[2] = {};                  // dv tiles j=0,1: dv = wave*32 + j*16 + mlane
    const int r = tid >> 1, hf = tid & 1;
    const int d2l = tid >> 4, cg = tid & 15;

    for (int n = 0; n < NCH; n++) {
        const int row0 = b * Lc + n * CHK;
        // 1. stage k-chunk (f32)
        {
            const float4* src = (const float4*)(kn + (size_t)(row0 + r) * HFD + h * FDc + hf * 8);
            *(float4*)(kcs + r * 16 + hf * 8)     = src[0];
            *(float4*)(kcs + r * 16 + hf * 8 + 4) = src[1];
        }
        __syncthreads();
        // 2. build K2t (bf16) + z partials (f32)
        {
            float zs_ = 0.f;
            unsigned short pk[8];
#pragma unroll
            for (int u = 0; u < 8; u++) {
                int c = cg * 8 + u;
                float p = kcs[c * 16 + bx] * kcs[c * 16 + d2l] * 0.25f;
                zs_ += p;
                pk[u] = f2bf(p);
            }
            uint4 w;
            w.x = pack2(pk[0], pk[1]); w.y = pack2(pk[2], pk[3]);
            w.z = pack2(pk[4], pk[5]); w.w = pack2(pk[6], pk[7]);
            *(uint4*)(K2t + d2l * 136 + cg * 8) = w;
            zp[d2l][cg] = zs_;
        }
        __syncthreads();
        // 3. exclusive-prefix writes (St from acc, zc from zpre)
        {
            size_t base = (((size_t)(bh * NCH + n) * 16 + bx) * 128) * 16;
#pragma unroll
            for (int j = 0; j < 2; j++) {
                int dv = wave * 32 + j * 16 + mlane;
                ushort4 pk;
                pk.x = f2bf(acc[j][0]); pk.y = f2bf(acc[j][1]);
                pk.z = f2bf(acc[j][2]); pk.w = f2bf(acc[j][3]);
                *(ushort4*)(St + base + (size_t)dv * 16 + quad * 4) = pk;
            }
            if (tid < 16) {
                float s = 0.f;
#pragma unroll
                for (int c = 0; c < 16; c++) s += zp[tid][c];
                zc[(size_t)(bh * NCH + n) * D2c + t0 + tid] = zpre[tid];
                zpre[tid] += s;
            }
        }
        // 4. MFMA update: acc += K2t @ V  (B-frags direct from global vT)
        {
            bf16x8 a[4];
#pragma unroll
            for (int ks = 0; ks < 4; ks++)
                a[ks] = *(const bf16x8*)(K2t + mlane * 136 + ks * 32 + quad * 8);
#pragma unroll
            for (int j = 0; j < 2; j++) {
                int dv = wave * 32 + j * 16 + mlane;
                const unsigned short* vrow = vT + (size_t)(h * 128 + dv) * ROWS + row0;
#pragma unroll
                for (int ks = 0; ks < 4; ks++) {
                    bf16x8 bfr = *(const bf16x8*)(vrow + ks * 32 + quad * 8);
                    acc[j] = __builtin_amdgcn_mfma_f32_16x16x32_bf16(a[ks], bfr, acc[j], 0, 0, 0);
                }
            }
        }
    }
}

// ---------------------------------------------------------------------------
// MFMA chunk output. Per (bh, n) block:
//   num1 = Q2 @ S_prefix (St bf16, tile-major layout), den1 = Q2 . z (fused)
//   P    = Q @ K^T (zero-padded K=32 MFMA), A = tril(P^2/16) -> LDS bf16
//   num2 = A @ V (via vT bf16 [dv][seq]),   den2 = rowsum(A)
//   o    = (num1+num2) / (den1+den2+eps)  -> bf16 row-major [4096][1536]
// ---------------------------------------------------------------------------
__global__ __launch_bounds__(256) void chunk_out_mfma(const float* __restrict__ qn,
                                                      const float* __restrict__ kn,
                                                      const unsigned short* __restrict__ St,
                                                      const float* __restrict__ z,
                                                      const unsigned short* __restrict__ vT,
                                                      unsigned short* __restrict__ o) {
    const int blk = blockIdx.x;
    const int n = blk & 15, bh = blk >> 4;
    const int h = bh % Hc, b = bh / Hc;
    const int row0 = b * Lc + n * CHK;
    const int tid = threadIdx.x;
    const int wave = tid >> 6, lane = tid & 63;
    const int mlane = lane & 15, quad = lane >> 4;
    const int wrow = (wave >> 1) * 64, wcol = (wave & 1) * 64;

    __shared__ __align__(16) unsigned char lds[61952];
    float* Qs   = (float*)lds;                           // [128][16] f32   8192
    float* zs   = (float*)(lds + 8192);                  // [256]           1024
    float* denp = (float*)(lds + 9216);                  // [2][128]        1024
    float* dinv = (float*)(lds + 10240);                 // [128]           512
    unsigned char* U = lds + 10752;
    unsigned short* Q2s = (unsigned short*)U;            // [128][40] bf16  10240
    unsigned short* Sts = (unsigned short*)(U + 10240);  // [128][40] bf16  10240
    unsigned short* Kb  = (unsigned short*)U;            // [128][32] bf16  8192
    unsigned short* Qb  = (unsigned short*)(U + 8192);   // [128][32] bf16  8192
    unsigned short* At  = (unsigned short*)(U + 16384);  // [128][136] bf16 34816
    unsigned short* Vs  = (unsigned short*)U;            // [128][40] bf16  10240

    // ---- load Qs (f32, full 16 floats per row) and zs ----
    {
        int r = tid >> 1, hf = tid & 1;
        const float4* src = (const float4*)(qn + (size_t)(row0 + r) * HFD + h * FDc + hf * 8);
        *(float4*)(Qs + r * 16 + hf * 8)     = src[0];
        *(float4*)(Qs + r * 16 + hf * 8 + 4) = src[1];
        if (tid < 64)
            ((float4*)zs)[tid] = ((const float4*)(z + ((size_t)bh * NCH + n) * D2c))[tid];
    }
    __syncthreads();

    const int qc = tid >> 1, qhalf = tid & 1;
    float qr[16];
#pragma unroll
    for (int ff = 0; ff < 16; ff++) qr[ff] = Qs[qc * 16 + ff];

    f32x4 acc[4][4] = {};
    float den1 = 0.f;
    const unsigned short* Stb = St + ((size_t)bh * NCH + n) * ((size_t)D2c * DVc);

    // ---- num1: K = 256 over d2 in 32-slabs ----
    for (int k0 = 0; k0 < 256; k0 += 32) {
        {
            unsigned short pk[16];
#pragma unroll
            for (int kk = 0; kk < 16; kk++) {
                int d2 = k0 + qhalf * 16 + kk;
                float val = qr[d2 >> 4] * qr[d2 & 15] * 0.25f;
                den1 += val * zs[d2];
                pk[kk] = f2bf(val);
            }
            uint4 w0, w1;
            w0.x = pack2(pk[0], pk[1]);  w0.y = pack2(pk[2], pk[3]);
            w0.z = pack2(pk[4], pk[5]);  w0.w = pack2(pk[6], pk[7]);
            w1.x = pack2(pk[8], pk[9]);  w1.y = pack2(pk[10], pk[11]);
            w1.z = pack2(pk[12], pk[13]); w1.w = pack2(pk[14], pk[15]);
            *(uint4*)(Q2s + qc * 40 + qhalf * 16) = w0;
            *(uint4*)(Q2s + qc * 40 + qhalf * 16 + 8) = w1;
        }
        {
            // St tile-major: element (dv=r, d2=k0+hf*16+s) at (k0/16+hf)*2048 + r*16 + s
            int r = tid >> 1, hf = tid & 1;
            const uint4* g = (const uint4*)(Stb + (size_t)((k0 >> 4) + hf) * 2048 + r * 16);
            uint4 d0 = g[0], d1 = g[1];
            *(uint4*)(Sts + r * 40 + hf * 16) = d0;
            *(uint4*)(Sts + r * 40 + hf * 16 + 8) = d1;
        }
        __syncthreads();
        bf16x8 a[4], bfr[4];
#pragma unroll
        for (int i = 0; i < 4; i++)
            a[i] = *(const bf16x8*)(Q2s + (wrow + i * 16 + mlane) * 40 + quad * 8);
#pragma unroll
        for (int j = 0; j < 4; j++)
            bfr[j] = *(const bf16x8*)(Sts + (wcol + j * 16 + mlane) * 40 + quad * 8);
#pragma unroll
        for (int i = 0; i < 4; i++)
#pragma unroll
            for (int j = 0; j < 4; j++)
                acc[i][j] = __builtin_amdgcn_mfma_f32_16x16x32_bf16(a[i], bfr[j], acc[i][j], 0, 0, 0);
        __syncthreads();
    }
    denp[qhalf * 128 + qc] = den1;

    // ---- build Qb, Kb zero-padded [128][32] ----
    {
        int r = tid >> 1, hf = tid & 1;
        if (hf == 0) {
            unsigned short pq[16], pkk[16];
#pragma unroll
            for (int ff = 0; ff < 16; ff++) pq[ff] = f2bf(Qs[r * 16 + ff]);
            const float* kg = kn + (size_t)(row0 + r) * HFD + h * FDc;
#pragma unroll
            for (int ff = 0; ff < 16; ff++) pkk[ff] = f2bf(kg[ff]);
            uint4 w;
            w.x = pack2(pq[0], pq[1]);  w.y = pack2(pq[2], pq[3]);
            w.z = pack2(pq[4], pq[5]);  w.w = pack2(pq[6], pq[7]);
            *(uint4*)(Qb + r * 32) = w;
            w.x = pack2(pq[8], pq[9]);  w.y = pack2(pq[10], pq[11]);
            w.z = pack2(pq[12], pq[13]); w.w = pack2(pq[14], pq[15]);
            *(uint4*)(Qb + r * 32 + 8) = w;
            w.x = pack2(pkk[0], pkk[1]);  w.y = pack2(pkk[2], pkk[3]);
            w.z = pack2(pkk[4], pkk[5]);  w.w = pack2(pkk[6], pkk[7]);
            *(uint4*)(Kb + r * 32) = w;
            w.x = pack2(pkk[8], pkk[9]);  w.y = pack2(pkk[10], pkk[11]);
            w.z = pack2(pkk[12], pkk[13]); w.w = pack2(pkk[14], pkk[15]);
            *(uint4*)(Kb + r * 32 + 8) = w;
        } else {
            uint4 zz = make_uint4(0, 0, 0, 0);
            *(uint4*)(Qb + r * 32 + 16) = zz;
            *(uint4*)(Qb + r * 32 + 24) = zz;
            *(uint4*)(Kb + r * 32 + 16) = zz;
            *(uint4*)(Kb + r * 32 + 24) = zz;
        }
    }
    __syncthreads();

    // ---- P = Q @ K^T, A = tril(P^2/16) ----
    {
        f32x4 pacc[4][4] = {};
        bf16x8 a[4], bfr[4];
#pragma unroll
        for (int i = 0; i < 4; i++)
            a[i] = *(const bf16x8*)(Qb + (wrow + i * 16 + mlane) * 32 + quad * 8);
#pragma unroll
        for (int j = 0; j < 4; j++)
            bfr[j] = *(const bf16x8*)(Kb + (wcol + j * 16 + mlane) * 32 + quad * 8);
#pragma unroll
        for (int i = 0; i < 4; i++)
#pragma unroll
            for (int j = 0; j < 4; j++)
                pacc[i][j] = __builtin_amdgcn_mfma_f32_16x16x32_bf16(a[i], bfr[j], pacc[i][j], 0, 0, 0);
#pragma unroll
        for (int i = 0; i < 4; i++)
#pragma unroll
            for (int j = 0; j < 4; j++) {
                int e = wcol + j * 16 + mlane;
#pragma unroll
                for (int r = 0; r < 4; r++) {
                    int c = wrow + i * 16 + quad * 4 + r;
                    float p = pacc[i][j][r];
                    float aval = (e <= c) ? p * p * 0.0625f : 0.f;
                    At[c * 136 + e] = f2bf(aval);
                }
            }
    }
    __syncthreads();

    // ---- dinv[c] = 1/(den1 + rowsum(A) + eps) ----
    if (tid < 128) {
        float rs = 0.f;
#pragma unroll
        for (int e8 = 0; e8 < 128; e8 += 8) {
            bf16x8 v8 = *(const bf16x8*)(At + tid * 136 + e8);
#pragma unroll
            for (int u = 0; u < 8; u++) rs += (float)v8[u];
        }
        dinv[tid] = 1.0f / (denp[tid] + denp[128 + tid] + rs + 1e-12f);
    }

    // ---- num2: A @ V, K = 128 over e in 32-slabs ----
    for (int e0 = 0; e0 < 128; e0 += 32) {
        {
            int r = tid >> 1, hf = tid & 1;
            const uint4* g = (const uint4*)(vT + (size_t)(h * 128 + r) * ROWS + row0 + e0 + hf * 16);
            uint4 d0 = g[0], d1 = g[1];
            *(uint4*)(Vs + r * 40 + hf * 16) = d0;
            *(uint4*)(Vs + r * 40 + hf * 16 + 8) = d1;
        }
        __syncthreads();
        bf16x8 a[4], bfr[4];
#pragma unroll
        for (int i = 0; i < 4; i++)
            a[i] = *(const bf16x8*)(At + (wrow + i * 16 + mlane) * 136 + e0 + quad * 8);
#pragma unroll
        for (int j = 0; j < 4; j++)
            bfr[j] = *(const bf16x8*)(Vs + (wcol + j * 16 + mlane) * 40 + quad * 8);
#pragma unroll
        for (int i = 0; i < 4; i++)
#pragma unroll
            for (int j = 0; j < 4; j++)
                acc[i][j] = __builtin_amdgcn_mfma_f32_16x16x32_bf16(a[i], bfr[j], acc[i][j], 0, 0, 0);
        __syncthreads();
    }

    // ---- epilogue ----
#pragma unroll
    for (int i = 0; i < 4; i++)
#pragma unroll
        for (int j = 0; j < 4; j++) {
            int col = h * 128 + wcol + j * 16 + mlane;
#pragma unroll
            for (int r = 0; r < 4; r++) {
                int c = wrow + i * 16 + quad * 4 + r;
                o[(size_t)(row0 + c) * HDV + col] = f2bf(acc[i][j][r] * dinv[c]);
            }
        }
}

// ---------------------------------------------------------------------------
extern "C" void kernel_launch(void* const* d_in, const int* in_sizes, int n_in,
                              void* d_out, int out_size, void* d_ws, size_t ws_size,
                              hipStream_t stream) {
    const void* hs = d_in[0];
    const void* Wq = d_in[1];
    const void* Wk = d_in[2];
    const void* Wv = d_in[3];
    const void* Wo = d_in[4];
    const void* gq = d_in[5];
    const void* bq = d_in[6];
    const void* gk = d_in[7];
    const void* bk = d_in[8];

    int* flag = (int*)d_ws;
    float* base = (float*)d_ws + 16;
    float* qpre = base;                                   // 4096*192 f32
    float* kpre = qpre + (size_t)ROWS * HFD;              // 4096*192 f32
    float* vreg = kpre + (size_t)ROWS * HFD;              // 25.2 MB region (St lives here)
    float* Sc   = vreg + (size_t)ROWS * HDV;              // 50 MB region (qk/Wqkt aliases)
    float* zc   = Sc + (size_t)Bc * Hc * NCH * D2c * DVc; // 384*256 f32
    float* fend = zc + (size_t)Bc * Hc * NCH * D2c;
    unsigned short* hsb = (unsigned short*)fend;          // 4096*1536 bf16
    unsigned short* ob  = hsb;                            // alias (hsb dead before ob)
    unsigned short* Wvt = hsb + (size_t)ROWS * DMc;       // 1536*1536 bf16
    unsigned short* Wot = Wvt + (size_t)DMc * HDV;        // 1536*1536 bf16
    unsigned short* vT  = Wot + (size_t)HDV * DMc;        // 1536*4096 bf16 (12.6 MB)
    // aliases into Sc region:
    float* qk = Sc;                                       // 4096*384 f32
    unsigned short* Wqkt = (unsigned short*)(Sc + (size_t)ROWS * NQK);  // 384*1536 bf16
    // St (bf16 exclusive-prefix state, tile-major) uses the old v region.
    unsigned short* St = (unsigned short*)vreg;           // 24*16*16*128*16 bf16 = 25.2 MB

    probe_dtype<<<1, 256, 0, stream>>>((const unsigned short*)hs, flag);

    // bf16 prep
    conv_bf16<<<(ROWS * DMc / 4 + 255) / 256, 256, 0, stream>>>(hs, hsb, ROWS * DMc / 4, flag);
    convT_bf16<<<dim3(HFD / 64, DMc / 64), 256, 0, stream>>>(Wq, Wqkt, DMc, HFD, flag);
    convT_bf16<<<dim3(HFD / 64, DMc / 64), 256, 0, stream>>>(Wk, Wqkt + (size_t)HFD * DMc, DMc, HFD, flag);
    convT_bf16<<<dim3(HDV / 64, DMc / 64), 256, 0, stream>>>(Wv, Wvt, DMc, HDV, flag);
    convT_bf16<<<dim3(DMc / 64, HDV / 64), 256, 0, stream>>>(Wo, Wot, HDV, DMc, flag);

    // qk = hs @ [Wq|Wk]
    gemm_mfma_bt<<<dim3(NQK / 128, ROWS / 128), 256, 0, stream>>>(
        hsb, Wqkt, qk, ROWS, NQK, DMc, 0, flag, nullptr);
    // vT = (hs @ Wv)^T bf16 only (no f32 C)
    gemm_mfma_bt<<<dim3(HDV / 128, ROWS / 128), 256, 0, stream>>>(
        hsb, Wvt, nullptr, ROWS, HDV, DMc, 3, flag, vT);

    ln_kernel<<<ROWS, HFD, 0, stream>>>(qk, qpre, kpre, gq, bq, gk, bk, flag);

    // fused state + prefix (replaces chunk_state + sprefix2 + zprefix)
    state_prefix_mfma<<<dim3(16, Bc * Hc), 256, 0, stream>>>(kpre, vT, St, zc);

    chunk_out_mfma<<<Bc * Hc * NCH, 256, 0, stream>>>(qpre, kpre, St, zc, vT, ob);

    // out = o @ Wo
    gemm_mfma_bt<<<dim3(DMc / 128, ROWS / 128), 256, 0, stream>>>(
        ob, Wot, d_out, ROWS, DMc, HDV, 2, flag, nullptr);
}

// Round 9
// 326.812 us; speedup vs baseline: 4.3380x; 1.0838x over previous
//
#include <hip/hip_runtime.h>
#include <hip/hip_bf16.h>
#include <math.h>

// Problem constants
#define Bc   2
#define Lc   2048
#define DMc  1536
#define Hc   12
#define FDc  16
#define DVc  128
#define D2c  256
#define CHK  128
#define NCH  16
#define ROWS (Bc*Lc)          // 4096
#define HFD  (Hc*FDc)         // 192
#define HDV  (Hc*DVc)         // 1536
#define NQK  (2*HFD)          // 384 fused q|k projection width

typedef __bf16 bf16x8 __attribute__((ext_vector_type(8)));
typedef float f32x4 __attribute__((ext_vector_type(4)));

__device__ __forceinline__ float bf2f(unsigned short u) {
    return __uint_as_float(((unsigned int)u) << 16);
}
__device__ __forceinline__ unsigned short f2bf(float v) {
    unsigned int u = __float_as_uint(v);
    unsigned int r = (u + 0x7FFFu + ((u >> 16) & 1u)) >> 16;
    return (unsigned short)r;
}
__device__ __forceinline__ unsigned int pack2(unsigned short a, unsigned short b) {
    return (unsigned int)a | ((unsigned int)b << 16);
}
__device__ __forceinline__ float ldin(const void* p, size_t i, int isf32) {
    return isf32 ? ((const float*)p)[i] : bf2f(((const unsigned short*)p)[i]);
}
__device__ __forceinline__ float scrubf(float v) {
    return (fabsf(v) < 1e30f) ? v : 0.f;
}

#define GLL16(g, l) __builtin_amdgcn_global_load_lds( \
    (const __attribute__((address_space(1))) unsigned int*)(g), \
    (__attribute__((address_space(3))) unsigned int*)(l), 16, 0, 0)

// ---------------------------------------------------------------------------
// Dtype probe: writes flag 0 = bf16 data, 1 = f32 data.
// ---------------------------------------------------------------------------
__global__ void probe_dtype(const unsigned short* __restrict__ hs, int* __restrict__ flag) {
    const int tid = threadIdx.x;
    int sane = 0;
    for (int i = tid; i < 1024; i += 256) {
        unsigned short b = hs[2 * i];
        int e = (b >> 7) & 0xFF;
        if (e >= 97 && e <= 157) sane++;
    }
    __shared__ int tot;
    if (tid == 0) tot = 0;
    __syncthreads();
    atomicAdd(&tot, sane);
    __syncthreads();
    if (tid == 0) *flag = (tot >= 614) ? 0 : 1;
}

// ---------------------------------------------------------------------------
// Elementwise convert to bf16 (4 elems/thread).
// ---------------------------------------------------------------------------
__global__ __launch_bounds__(256) void conv_bf16(const void* __restrict__ X,
                                                 unsigned short* __restrict__ Y,
                                                 int n4, const int* __restrict__ flagp) {
    const int f = *flagp;
    int i = blockIdx.x * 256 + threadIdx.x;
    if (i >= n4) return;
    if (f) {
        float4 x = ((const float4*)X)[i];
        ushort4 y;
        y.x = f2bf(x.x); y.y = f2bf(x.y); y.z = f2bf(x.z); y.w = f2bf(x.w);
        ((ushort4*)Y)[i] = y;
    } else {
        ((ushort4*)Y)[i] = ((const ushort4*)X)[i];
    }
}

// ---------------------------------------------------------------------------
// Transpose + convert: Wt[n][k] = bf16(W[k][n]). rows = K extent, cols = N extent.
// ---------------------------------------------------------------------------
__global__ __launch_bounds__(256) void convT_bf16(const void* __restrict__ W,
                                                  unsigned short* __restrict__ Wt,
                                                  int rows, int cols,
                                                  const int* __restrict__ flagp) {
    const int f = *flagp;
    __shared__ float tile[64][65];
    const int t = threadIdx.x;
    const int bx = blockIdx.x * 64;  // n
    const int by = blockIdx.y * 64;  // k
#pragma unroll
    for (int u = 0; u < 16; u++) {
        int idx = t + u * 256;
        int r = idx >> 6, c = idx & 63;
        tile[r][c] = ldin(W, (size_t)(by + r) * cols + bx + c, f);
    }
    __syncthreads();
#pragma unroll
    for (int u = 0; u < 16; u++) {
        int idx = t + u * 256;
        int r = idx >> 6, c = idx & 63;
        Wt[(size_t)(bx + r) * rows + by + c] = f2bf(tile[c][r]);
    }
}

// ---------------------------------------------------------------------------
// MFMA bf16 GEMM: C(MxN) = A(MxK) @ Bt(NxK)^T. 128x128 tile, 4 waves.
// cMode: 0 = C f32, 1 = C bf16, 2 = flagged, 3 = no C store (vTout only).
// Optional vTout: store C^T bf16 [N][M].
// ---------------------------------------------------------------------------
__global__ __launch_bounds__(256) void gemm_mfma_bt(const unsigned short* __restrict__ A,
                                                    const unsigned short* __restrict__ Bt,
                                                    void* __restrict__ C,
                                                    int M, int N, int K,
                                                    int cMode, const int* __restrict__ flagp,
                                                    unsigned short* __restrict__ vTout) {
    const int f = *flagp;
    const bool writeC = (cMode != 3);
    const bool cF32 = (cMode == 0) || (cMode == 2 && f == 1);
    __shared__ __align__(16) unsigned short As[128 * 32];
    __shared__ __align__(16) unsigned short Bs[128 * 32];
    const int tid = threadIdx.x;
    const int wave = tid >> 6, lane = tid & 63;
    const int row0 = blockIdx.y * 128, col0 = blockIdx.x * 128;
    const int wrow = (wave >> 1) * 64, wcol = (wave & 1) * 64;
    const int mlane = lane & 15, quad = lane >> 4;

    const unsigned short* Ab = A + (size_t)row0 * K;
    const unsigned short* Bb = Bt + (size_t)col0 * K;
    const int r0 = tid >> 2;
    const int kc = (tid & 3) * 8;
    const size_t off0 = (size_t)r0 * K + kc;
    const size_t off1 = (size_t)(r0 + 64) * K + kc;
    char* AsW = (char*)As + wave * 1024;
    char* BsW = (char*)Bs + wave * 1024;

    f32x4 acc[4][4] = {};

    for (int k0 = 0; k0 < K; k0 += 32) {
        GLL16(Ab + off0 + k0, AsW);
        GLL16(Ab + off1 + k0, AsW + 4096);
        GLL16(Bb + off0 + k0, BsW);
        GLL16(Bb + off1 + k0, BsW + 4096);
        __syncthreads();
        bf16x8 a[4], b[4];
#pragma unroll
        for (int i = 0; i < 4; i++)
            a[i] = *(const bf16x8*)&As[(wrow + i * 16 + mlane) * 32 + quad * 8];
#pragma unroll
        for (int j = 0; j < 4; j++)
            b[j] = *(const bf16x8*)&Bs[(wcol + j * 16 + mlane) * 32 + quad * 8];
#pragma unroll
        for (int i = 0; i < 4; i++)
#pragma unroll
            for (int j = 0; j < 4; j++)
                acc[i][j] = __builtin_amdgcn_mfma_f32_16x16x32_bf16(a[i], b[j], acc[i][j], 0, 0, 0);
        __syncthreads();
    }

#pragma unroll
    for (int i = 0; i < 4; i++)
#pragma unroll
        for (int j = 0; j < 4; j++) {
            const int col = col0 + wcol + j * 16 + mlane;
            if (writeC) {
#pragma unroll
                for (int r = 0; r < 4; r++) {
                    const int row = row0 + wrow + i * 16 + quad * 4 + r;
                    float vv = acc[i][j][r];
                    if (cF32) ((float*)C)[(size_t)row * N + col] = vv;
                    else      ((unsigned short*)C)[(size_t)row * N + col] = f2bf(vv);
                }
            }
            if (vTout) {
                ushort4 pk;
                pk.x = f2bf(acc[i][j][0]); pk.y = f2bf(acc[i][j][1]);
                pk.z = f2bf(acc[i][j][2]); pk.w = f2bf(acc[i][j][3]);
                *(ushort4*)(vTout + (size_t)col * M + row0 + wrow + i * 16 + quad * 4) = pk;
            }
        }
}

// ---------------------------------------------------------------------------
// Fused LayerNorm: reads fused qk (4096 x 384), writes qpre/kpre (4096 x 192).
// ---------------------------------------------------------------------------
__global__ __launch_bounds__(192) void ln_kernel(const float* __restrict__ qk,
                                                 float* __restrict__ q, float* __restrict__ k,
                                                 const void* __restrict__ gq,
                                                 const void* __restrict__ bq,
                                                 const void* __restrict__ gk,
                                                 const void* __restrict__ bk,
                                                 const int* __restrict__ flagp) {
    const int f = *flagp;
    const int row = blockIdx.x, t = threadIdx.x;
    float vq = qk[(size_t)row * NQK + t];
    float vk = qk[(size_t)row * NQK + HFD + t];
    float s[4] = {vq, vq * vq, vk, vk * vk};
    __shared__ float part[4][3];
    const int w = t >> 6, lane = t & 63;
#pragma unroll
    for (int i = 0; i < 4; i++) {
        float v = s[i];
        for (int off = 32; off; off >>= 1) v += __shfl_down(v, off);
        if (lane == 0) part[i][w] = v;
    }
    __syncthreads();
    float sq  = part[0][0] + part[0][1] + part[0][2];
    float sq2 = part[1][0] + part[1][1] + part[1][2];
    float sk  = part[2][0] + part[2][1] + part[2][2];
    float sk2 = part[3][0] + part[3][1] + part[3][2];
    const float inv = 1.0f / (float)HFD;
    float muq = sq * inv, muk = sk * inv;
    float varq = sq2 * inv - muq * muq;
    float vark = sk2 * inv - muk * muk;
    float oq = (vq - muq) * rsqrtf(varq + 1e-5f) * ldin(gq, t, f) + ldin(bq, t, f);
    float ok = (vk - muk) * rsqrtf(vark + 1e-5f) * ldin(gk, t, f) + ldin(bk, t, f);
    q[(size_t)row * HFD + t] = oq;
    k[(size_t)row * HFD + t] = ok;
}

// ---------------------------------------------------------------------------
// Fused chunk-state + exclusive prefix + z prefix, MFMA.
// grid = (16 d2-tiles, 2 dv-halves, 24 bh), 256 threads (4 waves).
// Block owns d2 range [bx*16, bx*16+16) x 64 dv (half by) for one bh; iterates
// the 16 chunks keeping the running S-prefix in MFMA f32 accumulators, writing
// the EXCLUSIVE prefix as bf16 St[bh][n][t][dv][16] before each chunk update.
// z exclusive prefix (f32) -> zc[bh][n][256], written by by==0 blocks only.
// V chunk staged in LDS (coalesced 64B/thread) to avoid per-lane gathers.
// ---------------------------------------------------------------------------
__global__ __launch_bounds__(256) void state_prefix_mfma(const float* __restrict__ kn,
                                                         const unsigned short* __restrict__ vT,
                                                         unsigned short* __restrict__ St,
                                                         float* __restrict__ zc) {
    const int bx = blockIdx.x;          // d2 tile = i index
    const int by = blockIdx.y;          // dv half
    const int bh = blockIdx.z;
    const int h = bh % Hc, b = bh / Hc;
    const int t0 = bx * 16;
    const int tid = threadIdx.x;
    const int wave = tid >> 6, lane = tid & 63;
    const int mlane = lane & 15, quad = lane >> 4;

    __shared__ __align__(16) float kcs[CHK * FDc];          // [c][16] f32, 8 KB
    __shared__ __align__(16) unsigned short K2t[16 * 136];  // [d2l][c pad]  4.25 KB
    __shared__ __align__(16) unsigned short Vs[64 * 136];   // [dvL][c pad] 17 KB
    __shared__ float zp[16][17];
    __shared__ float zpre[16];
    if (tid < 16) zpre[tid] = 0.f;

    f32x4 acc = {};                     // dv = by*64 + wave*16 + mlane
    const int kr = tid >> 1, khf = tid & 1;
    const int d2l = tid & 15, cg = tid >> 4;   // conflict-free kcs access
    const int vrow = tid >> 2, vseg = tid & 3; // V staging: 4 thr/row, 64B each
    const int dvL = wave * 16 + mlane;

    for (int n = 0; n < NCH; n++) {
        const int row0 = b * Lc + n * CHK;
        __syncthreads();   // protect kcs/K2t/Vs from previous iteration's readers
        // 1. stage k-chunk (f32) + V chunk (bf16, 32 ushorts = 64B per thread)
        {
            const float4* src = (const float4*)(kn + (size_t)(row0 + kr) * HFD + h * FDc + khf * 8);
            *(float4*)(kcs + kr * 16 + khf * 8)     = src[0];
            *(float4*)(kcs + kr * 16 + khf * 8 + 4) = src[1];
            const uint4* g = (const uint4*)(vT + (size_t)(h * 128 + by * 64 + vrow) * ROWS + row0 + vseg * 32);
            *(uint4*)(Vs + vrow * 136 + vseg * 32)      = g[0];
            *(uint4*)(Vs + vrow * 136 + vseg * 32 + 8)  = g[1];
            *(uint4*)(Vs + vrow * 136 + vseg * 32 + 16) = g[2];
            *(uint4*)(Vs + vrow * 136 + vseg * 32 + 24) = g[3];
        }
        __syncthreads();
        // 2. build K2t (bf16) + z partials; kcs[c*16+d2l] consecutive-bank
        {
            float zs_ = 0.f;
            unsigned short pk[8];
#pragma unroll
            for (int u = 0; u < 8; u++) {
                int c = cg * 8 + u;
                float p = kcs[c * 16 + bx] * kcs[c * 16 + d2l] * 0.25f;
                zs_ += p;
                pk[u] = f2bf(p);
            }
            uint4 w;
            w.x = pack2(pk[0], pk[1]); w.y = pack2(pk[2], pk[3]);
            w.z = pack2(pk[4], pk[5]); w.w = pack2(pk[6], pk[7]);
            *(uint4*)(K2t + d2l * 136 + cg * 8) = w;
            zp[d2l][cg] = zs_;
        }
        __syncthreads();
        // 3. exclusive-prefix writes (St from acc, zc from zpre)
        {
            size_t base = (((size_t)(bh * NCH + n) * 16 + bx) * 128) * 16;
            int dv = by * 64 + dvL;
            ushort4 pk;
            pk.x = f2bf(acc[0]); pk.y = f2bf(acc[1]);
            pk.z = f2bf(acc[2]); pk.w = f2bf(acc[3]);
            *(ushort4*)(St + base + (size_t)dv * 16 + quad * 4) = pk;
            if (tid < 16) {
                float s = 0.f;
#pragma unroll
                for (int c = 0; c < 16; c++) s += zp[tid][c];
                if (by == 0)
                    zc[(size_t)(bh * NCH + n) * D2c + t0 + tid] = zpre[tid];
                zpre[tid] += s;
            }
        }
        // 4. MFMA update: acc += K2t @ Vs  (both from LDS)
        {
#pragma unroll
            for (int ks = 0; ks < 4; ks++) {
                bf16x8 a = *(const bf16x8*)(K2t + mlane * 136 + ks * 32 + quad * 8);
                bf16x8 bfr = *(const bf16x8*)(Vs + dvL * 136 + ks * 32 + quad * 8);
                acc = __builtin_amdgcn_mfma_f32_16x16x32_bf16(a, bfr, acc, 0, 0, 0);
            }
        }
    }
}

// ---------------------------------------------------------------------------
// MFMA chunk output. Per (bh, n) block:
//   num1 = Q2 @ S_prefix (St bf16, tile-major layout), den1 = Q2 . z (fused)
//   P    = Q @ K^T (zero-padded K=32 MFMA), A = tril(P^2/16) -> LDS bf16
//   num2 = A @ V (via vT bf16 [dv][seq]),   den2 = rowsum(A)
//   o    = (num1+num2) / (den1+den2+eps)  -> bf16 row-major [4096][1536]
// ---------------------------------------------------------------------------
__global__ __launch_bounds__(256) void chunk_out_mfma(const float* __restrict__ qn,
                                                      const float* __restrict__ kn,
                                                      const unsigned short* __restrict__ St,
                                                      const float* __restrict__ z,
                                                      const unsigned short* __restrict__ vT,
                                                      unsigned short* __restrict__ o) {
    const int blk = blockIdx.x;
    const int n = blk & 15, bh = blk >> 4;
    const int h = bh % Hc, b = bh / Hc;
    const int row0 = b * Lc + n * CHK;
    const int tid = threadIdx.x;
    const int wave = tid >> 6, lane = tid & 63;
    const int mlane = lane & 15, quad = lane >> 4;
    const int wrow = (wave >> 1) * 64, wcol = (wave & 1) * 64;

    __shared__ __align__(16) unsigned char lds[61952];
    float* Qs   = (float*)lds;                           // [128][16] f32   8192
    float* zs   = (float*)(lds + 8192);                  // [256]           1024
    float* denp = (float*)(lds + 9216);                  // [2][128]        1024
    float* dinv = (float*)(lds + 10240);                 // [128]           512
    unsigned char* U = lds + 10752;
    unsigned short* Q2s = (unsigned short*)U;            // [128][40] bf16  10240
    unsigned short* Sts = (unsigned short*)(U + 10240);  // [128][40] bf16  10240
    unsigned short* Kb  = (unsigned short*)U;            // [128][32] bf16  8192
    unsigned short* Qb  = (unsigned short*)(U + 8192);   // [128][32] bf16  8192
    unsigned short* At  = (unsigned short*)(U + 16384);  // [128][136] bf16 34816
    unsigned short* Vs  = (unsigned short*)U;            // [128][40] bf16  10240

    // ---- load Qs (f32, full 16 floats per row) and zs ----
    {
        int r = tid >> 1, hf = tid & 1;
        const float4* src = (const float4*)(qn + (size_t)(row0 + r) * HFD + h * FDc + hf * 8);
        *(float4*)(Qs + r * 16 + hf * 8)     = src[0];
        *(float4*)(Qs + r * 16 + hf * 8 + 4) = src[1];
        if (tid < 64)
            ((float4*)zs)[tid] = ((const float4*)(z + ((size_t)bh * NCH + n) * D2c))[tid];
    }
    __syncthreads();

    const int qc = tid >> 1, qhalf = tid & 1;
    float qr[16];
#pragma unroll
    for (int ff = 0; ff < 16; ff++) qr[ff] = Qs[qc * 16 + ff];

    f32x4 acc[4][4] = {};
    float den1 = 0.f;
    const unsigned short* Stb = St + ((size_t)bh * NCH + n) * ((size_t)D2c * DVc);

    // ---- num1: K = 256 over d2 in 32-slabs ----
    for (int k0 = 0; k0 < 256; k0 += 32) {
        {
            unsigned short pk[16];
#pragma unroll
            for (int kk = 0; kk < 16; kk++) {
                int d2 = k0 + qhalf * 16 + kk;
                float val = qr[d2 >> 4] * qr[d2 & 15] * 0.25f;
                den1 += val * zs[d2];
                pk[kk] = f2bf(val);
            }
            uint4 w0, w1;
            w0.x = pack2(pk[0], pk[1]);  w0.y = pack2(pk[2], pk[3]);
            w0.z = pack2(pk[4], pk[5]);  w0.w = pack2(pk[6], pk[7]);
            w1.x = pack2(pk[8], pk[9]);  w1.y = pack2(pk[10], pk[11]);
            w1.z = pack2(pk[12], pk[13]); w1.w = pack2(pk[14], pk[15]);
            *(uint4*)(Q2s + qc * 40 + qhalf * 16) = w0;
            *(uint4*)(Q2s + qc * 40 + qhalf * 16 + 8) = w1;
        }
        {
            // St tile-major: element (dv=r, d2=k0+hf*16+s) at (k0/16+hf)*2048 + r*16 + s
            int r = tid >> 1, hf = tid & 1;
            const uint4* g = (const uint4*)(Stb + (size_t)((k0 >> 4) + hf) * 2048 + r * 16);
            uint4 d0 = g[0], d1 = g[1];
            *(uint4*)(Sts + r * 40 + hf * 16) = d0;
            *(uint4*)(Sts + r * 40 + hf * 16 + 8) = d1;
        }
        __syncthreads();
        bf16x8 a[4], bfr[4];
#pragma unroll
        for (int i = 0; i < 4; i++)
            a[i] = *(const bf16x8*)(Q2s + (wrow + i * 16 + mlane) * 40 + quad * 8);
#pragma unroll
        for (int j = 0; j < 4; j++)
            bfr[j] = *(const bf16x8*)(Sts + (wcol + j * 16 + mlane) * 40 + quad * 8);
#pragma unroll
        for (int i = 0; i < 4; i++)
#pragma unroll
            for (int j = 0; j < 4; j++)
                acc[i][j] = __builtin_amdgcn_mfma_f32_16x16x32_bf16(a[i], bfr[j], acc[i][j], 0, 0, 0);
        __syncthreads();
    }
    denp[qhalf * 128 + qc] = den1;

    // ---- build Qb, Kb zero-padded [128][32] ----
    {
        int r = tid >> 1, hf = tid & 1;
        if (hf == 0) {
            unsigned short pq[16], pkk[16];
#pragma unroll
            for (int ff = 0; ff < 16; ff++) pq[ff] = f2bf(Qs[r * 16 + ff]);
            const float* kg = kn + (size_t)(row0 + r) * HFD + h * FDc;
#pragma unroll
            for (int ff = 0; ff < 16; ff++) pkk[ff] = f2bf(kg[ff]);
            uint4 w;
            w.x = pack2(pq[0], pq[1]);  w.y = pack2(pq[2], pq[3]);
            w.z = pack2(pq[4], pq[5]);  w.w = pack2(pq[6], pq[7]);
            *(uint4*)(Qb + r * 32) = w;
            w.x = pack2(pq[8], pq[9]);  w.y = pack2(pq[10], pq[11]);
            w.z = pack2(pq[12], pq[13]); w.w = pack2(pq[14], pq[15]);
            *(uint4*)(Qb + r * 32 + 8) = w;
            w.x = pack2(pkk[0], pkk[1]);  w.y = pack2(pkk[2], pkk[3]);
            w.z = pack2(pkk[4], pkk[5]);  w.w = pack2(pkk[6], pkk[7]);
            *(uint4*)(Kb + r * 32) = w;
            w.x = pack2(pkk[8], pkk[9]);  w.y = pack2(pkk[10], pkk[11]);
            w.z = pack2(pkk[12], pkk[13]); w.w = pack2(pkk[14], pkk[15]);
            *(uint4*)(Kb + r * 32 + 8) = w;
        } else {
            uint4 zz = make_uint4(0, 0, 0, 0);
            *(uint4*)(Qb + r * 32 + 16) = zz;
            *(uint4*)(Qb + r * 32 + 24) = zz;
            *(uint4*)(Kb + r * 32 + 16) = zz;
            *(uint4*)(Kb + r * 32 + 24) = zz;
        }
    }
    __syncthreads();

    // ---- P = Q @ K^T, A = tril(P^2/16) ----
    {
        f32x4 pacc[4][4] = {};
        bf16x8 a[4], bfr[4];
#pragma unroll
        for (int i = 0; i < 4; i++)
            a[i] = *(const bf16x8*)(Qb + (wrow + i * 16 + mlane) * 32 + quad * 8);
#pragma unroll
        for (int j = 0; j < 4; j++)
            bfr[j] = *(const bf16x8*)(Kb + (wcol + j * 16 + mlane) * 32 + quad * 8);
#pragma unroll
        for (int i = 0; i < 4; i++)
#pragma unroll
            for (int j = 0; j < 4; j++)
                pacc[i][j] = __builtin_amdgcn_mfma_f32_16x16x32_bf16(a[i], bfr[j], pacc[i][j], 0, 0, 0);
#pragma unroll
        for (int i = 0; i < 4; i++)
#pragma unroll
            for (int j = 0; j < 4; j++) {
                int e = wcol + j * 16 + mlane;
#pragma unroll
                for (int r = 0; r < 4; r++) {
                    int c = wrow + i * 16 + quad * 4 + r;
                    float p = pacc[i][j][r];
                    float aval = (e <= c) ? p * p * 0.0625f : 0.f;
                    At[c * 136 + e] = f2bf(aval);
                }
            }
    }
    __syncthreads();

    // ---- dinv[c] = 1/(den1 + rowsum(A) + eps) ----
    if (tid < 128) {
        float rs = 0.f;
#pragma unroll
        for (int e8 = 0; e8 < 128; e8 += 8) {
            bf16x8 v8 = *(const bf16x8*)(At + tid * 136 + e8);
#pragma unroll
            for (int u = 0; u < 8; u++) rs += (float)v8[u];
        }
        dinv[tid] = 1.0f / (denp[tid] + denp[128 + tid] + rs + 1e-12f);
    }

    // ---- num2: A @ V, K = 128 over e in 32-slabs ----
    for (int e0 = 0; e0 < 128; e0 += 32) {
        {
            int r = tid >> 1, hf = tid & 1;
            const uint4* g = (const uint4*)(vT + (size_t)(h * 128 + r) * ROWS + row0 + e0 + hf * 16);
            uint4 d0 = g[0], d1 = g[1];
            *(uint4*)(Vs + r * 40 + hf * 16) = d0;
            *(uint4*)(Vs + r * 40 + hf * 16 + 8) = d1;
        }
        __syncthreads();
        bf16x8 a[4], bfr[4];
#pragma unroll
        for (int i = 0; i < 4; i++)
            a[i] = *(const bf16x8*)(At + (wrow + i * 16 + mlane) * 136 + e0 + quad * 8);
#pragma unroll
        for (int j = 0; j < 4; j++)
            bfr[j] = *(const bf16x8*)(Vs + (wcol + j * 16 + mlane) * 40 + quad * 8);
#pragma unroll
        for (int i = 0; i < 4; i++)
#pragma unroll
            for (int j = 0; j < 4; j++)
                acc[i][j] = __builtin_amdgcn_mfma_f32_16x16x32_bf16(a[i], bfr[j], acc[i][j], 0, 0, 0);
        __syncthreads();
    }

    // ---- epilogue ----
#pragma unroll
    for (int i = 0; i < 4; i++)
#pragma unroll
        for (int j = 0; j < 4; j++) {
            int col = h * 128 + wcol + j * 16 + mlane;
#pragma unroll
            for (int r = 0; r < 4; r++) {
                int c = wrow + i * 16 + quad * 4 + r;
                o[(size_t)(row0 + c) * HDV + col] = f2bf(acc[i][j][r] * dinv[c]);
            }
        }
}

// ---------------------------------------------------------------------------
extern "C" void kernel_launch(void* const* d_in, const int* in_sizes, int n_in,
                              void* d_out, int out_size, void* d_ws, size_t ws_size,
                              hipStream_t stream) {
    const void* hs = d_in[0];
    const void* Wq = d_in[1];
    const void* Wk = d_in[2];
    const void* Wv = d_in[3];
    const void* Wo = d_in[4];
    const void* gq = d_in[5];
    const void* bq = d_in[6];
    const void* gk = d_in[7];
    const void* bk = d_in[8];

    int* flag = (int*)d_ws;
    float* base = (float*)d_ws + 16;
    float* qpre = base;                                   // 4096*192 f32
    float* kpre = qpre + (size_t)ROWS * HFD;              // 4096*192 f32
    float* vreg = kpre + (size_t)ROWS * HFD;              // 25.2 MB region (St lives here)
    float* Sc   = vreg + (size_t)ROWS * HDV;              // 50 MB region (qk/Wqkt aliases)
    float* zc   = Sc + (size_t)Bc * Hc * NCH * D2c * DVc; // 384*256 f32
    float* fend = zc + (size_t)Bc * Hc * NCH * D2c;
    unsigned short* hsb = (unsigned short*)fend;          // 4096*1536 bf16
    unsigned short* ob  = hsb;                            // alias (hsb dead before ob)
    unsigned short* Wvt = hsb + (size_t)ROWS * DMc;       // 1536*1536 bf16
    unsigned short* Wot = Wvt + (size_t)DMc * HDV;        // 1536*1536 bf16
    unsigned short* vT  = Wot + (size_t)HDV * DMc;        // 1536*4096 bf16 (12.6 MB)
    // aliases into Sc region:
    float* qk = Sc;                                       // 4096*384 f32
    unsigned short* Wqkt = (unsigned short*)(Sc + (size_t)ROWS * NQK);  // 384*1536 bf16
    // St (bf16 exclusive-prefix state, tile-major) uses the old v region.
    unsigned short* St = (unsigned short*)vreg;           // 24*16*16*128*16 bf16 = 25.2 MB

    probe_dtype<<<1, 256, 0, stream>>>((const unsigned short*)hs, flag);

    // bf16 prep
    conv_bf16<<<(ROWS * DMc / 4 + 255) / 256, 256, 0, stream>>>(hs, hsb, ROWS * DMc / 4, flag);
    convT_bf16<<<dim3(HFD / 64, DMc / 64), 256, 0, stream>>>(Wq, Wqkt, DMc, HFD, flag);
    convT_bf16<<<dim3(HFD / 64, DMc / 64), 256, 0, stream>>>(Wk, Wqkt + (size_t)HFD * DMc, DMc, HFD, flag);
    convT_bf16<<<dim3(HDV / 64, DMc / 64), 256, 0, stream>>>(Wv, Wvt, DMc, HDV, flag);
    convT_bf16<<<dim3(DMc / 64, HDV / 64), 256, 0, stream>>>(Wo, Wot, HDV, DMc, flag);

    // qk = hs @ [Wq|Wk]
    gemm_mfma_bt<<<dim3(NQK / 128, ROWS / 128), 256, 0, stream>>>(
        hsb, Wqkt, qk, ROWS, NQK, DMc, 0, flag, nullptr);
    // vT = (hs @ Wv)^T bf16 only (no f32 C)
    gemm_mfma_bt<<<dim3(HDV / 128, ROWS / 128), 256, 0, stream>>>(
        hsb, Wvt, nullptr, ROWS, HDV, DMc, 3, flag, vT);

    ln_kernel<<<ROWS, HFD, 0, stream>>>(qk, qpre, kpre, gq, bq, gk, bk, flag);

    // fused state + prefix (dv split in 2 for occupancy; LDS-staged V)
    state_prefix_mfma<<<dim3(16, 2, Bc * Hc), 256, 0, stream>>>(kpre, vT, St, zc);

    chunk_out_mfma<<<Bc * Hc * NCH, 256, 0, stream>>>(qpre, kpre, St, zc, vT, ob);

    // out = o @ Wo
    gemm_mfma_bt<<<dim3(DMc / 128, ROWS / 128), 256, 0, stream>>>(
        ob, Wot, d_out, ROWS, DMc, HDV, 2, flag, nullptr);
}